// Round 7
// baseline (222.856 us; speedup 1.0000x reference)
//
#include <hip/hip_runtime.h>
#include <hip/hip_bf16.h>

typedef short short8 __attribute__((ext_vector_type(8)));
typedef short short4v __attribute__((ext_vector_type(4)));
typedef float floatx4 __attribute__((ext_vector_type(4)));
typedef unsigned int uint4v __attribute__((ext_vector_type(4)));

constexpr int Bc = 2, Sc = 4096, Dc = 512, Hc = 8, DKc = 64;
constexpr int Mc = Bc * Sc;  // 8192

static __device__ __forceinline__ unsigned short f2bf(float f) {
  unsigned int u = __builtin_bit_cast(unsigned int, f);
  unsigned int rb = ((u >> 16) & 1u) + 0x7fffu;
  return (unsigned short)((u + rb) >> 16);
}
// hardware packed f32x2 -> bf16x2 (RNE), 1 instruction
static __device__ __forceinline__ unsigned int cvt_pk_bf16(float lo, float hi) {
  unsigned int r;
  asm("v_cvt_pk_bf16_f32 %0, %1, %2" : "=v"(r) : "v"(lo), "v"(hi));
  return r;
}
// 2^x, 1 instruction
static __device__ __forceinline__ float exp2_fast(float x) {
  float r;
  asm("v_exp_f32 %0, %1" : "=v"(r) : "v"(x));
  return r;
}

// ---------------- weight cast ------------------------------------------------
__global__ __launch_bounds__(256) void cast_w(
    const float* __restrict__ a, const float* __restrict__ b,
    const float* __restrict__ c, const float* __restrict__ d,
    unsigned short* __restrict__ out) {
  const float* srcs[4] = {a, b, c, d};
  const int m = blockIdx.y;
  const int i = (blockIdx.x * 256 + threadIdx.x) * 4;
  float4 v = *(const float4*)(srcs[m] + i);
  unsigned short t4[4] = {f2bf(v.x), f2bf(v.y), f2bf(v.z), f2bf(v.w)};
  *(short4v*)(out + (size_t)m * (Dc * Dc) + i) = *(short4v*)t4;
}

// ---------------- GEMM: Y[M,N] = X[M,K] @ W[N,K]^T ---------------------------
// BM=128, BN=64 -> grid (N/64, M/128) = 512 blocks = 2 blocks/CU (was 1).
template <int IN_F32, int OUT_F32>
__global__ __launch_bounds__(256) void gemm_bt(
    const void* __restrict__ Xv, const unsigned short* __restrict__ Wb,
    void* __restrict__ Yv, int Mdim, int N, int K) {
  constexpr int BM = 128, BN = 64, BK = 32, LDP = 40;
  __shared__ unsigned short As[BM * LDP];
  __shared__ unsigned short Bs[BN * LDP];
  const int tid = threadIdx.x;
  const int lane = tid & 63, wid = tid >> 6;
  const int wm = wid >> 1, wn = wid & 1;  // 2x2 waves: 64-row x 32-col tiles
  const int bm = blockIdx.y * BM, bn = blockIdx.x * BN;
  const int rq = lane & 15, kk8 = (lane >> 4) * 8;
  const int sr = tid >> 1, sc = (tid & 1) * 16;   // As staging
  const int brow = tid >> 2, bc8 = (tid & 3) * 8; // Bs staging

  floatx4 acc[4][2] = {};

  for (int k0 = 0; k0 < K; k0 += BK) {
    if (IN_F32) {
      const float* src = (const float*)Xv + (size_t)(bm + sr) * K + k0 + sc;
      unsigned int t2[8];
#pragma unroll
      for (int i = 0; i < 4; ++i) {
        float4 v = *(const float4*)(src + i * 4);
        t2[i * 2 + 0] = cvt_pk_bf16(v.x, v.y);
        t2[i * 2 + 1] = cvt_pk_bf16(v.z, v.w);
      }
      uint4v u0 = {t2[0], t2[1], t2[2], t2[3]};
      uint4v u1 = {t2[4], t2[5], t2[6], t2[7]};
      *(uint4v*)&As[sr * LDP + sc] = u0;
      *(uint4v*)&As[sr * LDP + sc + 8] = u1;
    } else {
      const unsigned short* src =
          (const unsigned short*)Xv + (size_t)(bm + sr) * K + k0 + sc;
      *(short8*)&As[sr * LDP + sc] = *(const short8*)src;
      *(short8*)&As[sr * LDP + sc + 8] = *(const short8*)(src + 8);
    }
    *(short8*)&Bs[brow * LDP + bc8] =
        *(const short8*)(Wb + (size_t)(bn + brow) * K + k0 + bc8);
    __syncthreads();

    short8 af[4], bfr[2];
#pragma unroll
    for (int mi = 0; mi < 4; ++mi)
      af[mi] = *(const short8*)&As[(wm * 64 + mi * 16 + rq) * LDP + kk8];
#pragma unroll
    for (int ni = 0; ni < 2; ++ni)
      bfr[ni] = *(const short8*)&Bs[(wn * 32 + ni * 16 + rq) * LDP + kk8];
#pragma unroll
    for (int mi = 0; mi < 4; ++mi)
#pragma unroll
      for (int ni = 0; ni < 2; ++ni)
        acc[mi][ni] = __builtin_amdgcn_mfma_f32_16x16x32_bf16(
            af[mi], bfr[ni], acc[mi][ni], 0, 0, 0);
    __syncthreads();
  }

#pragma unroll
  for (int mi = 0; mi < 4; ++mi)
#pragma unroll
    for (int ni = 0; ni < 2; ++ni)
#pragma unroll
      for (int j = 0; j < 4; ++j) {
        int r = bm + wm * 64 + mi * 16 + (lane >> 4) * 4 + j;
        int c = bn + wn * 32 + ni * 16 + rq;
        float v = acc[mi][ni][j];
        if (OUT_F32)
          ((float*)Yv)[(size_t)r * N + c] = v;
        else
          ((unsigned short*)Yv)[(size_t)r * N + c] = f2bf(v);
      }
}

// ---------------- V transpose: vt[b][c][s] = vb[b][s][c] ---------------------
__global__ __launch_bounds__(256) void transpose_v(
    const unsigned short* __restrict__ vb, unsigned short* __restrict__ vt) {
  constexpr int LDT = 65;
  __shared__ unsigned short T[64 * LDT];
  const int tid = threadIdx.x;
  const int s0 = blockIdx.x * 64, c0 = blockIdx.y * 64, b = blockIdx.z;
  const int r = tid >> 2, cs = (tid & 3) * 16;
  const unsigned short* src = vb + ((size_t)b * Sc + s0 + r) * Dc + c0 + cs;
  *(short8*)&T[r * LDT + cs] = *(const short8*)src;
  *(short8*)&T[r * LDT + cs + 8] = *(const short8*)(src + 8);
  __syncthreads();
  unsigned short* dst = vt + ((size_t)b * Dc + c0 + r) * Sc + s0 + cs;
  unsigned short tmp[16];
#pragma unroll
  for (int j = 0; j < 16; ++j) tmp[j] = T[(cs + j) * LDT + r];
  *(short8*)dst = *(short8*)&tmp[0];
  *(short8*)(dst + 8) = *(short8*)&tmp[8];
}

// ---------------- flash attention --------------------------------------------
// 8 waves: g = wid>>2 = key-half group, w = wid&3 = q-wave (16 q-rows each).
// Block = 64 q-rows -> grid 64x16 = 1024 blocks -> 3 blocks/CU (LDS 51.2KB).
// Swapped QK^T (s = mfma(K,Q)): lane holds 16 scores for q = lane&15.
// Softmax in exp2 domain (C2 = 0.125*log2e folded into one fma constant).
// launch_bounds min-waves stays 4: 6 forced spills in R5 (800MB scratch).
__global__ __launch_bounds__(512, 4) void attn_fwd(
    const unsigned short* __restrict__ Qp, const unsigned short* __restrict__ Kp,
    const unsigned short* __restrict__ Vtp, unsigned short* __restrict__ Op) {
  constexpr int LDPS = 72;
  // LDS bytes: Ks [0,16384) 2g x [64][64] swz; Vs [16384,32768) same;
  // Ps [32768,51200) 8 waves x [16][72]. Merge overlay: MO f32[64][64] @0,
  // ML f32[64][2] @32768.
  __shared__ unsigned char smem[51200];
  unsigned short* KsB = (unsigned short*)smem;
  unsigned short* VsB = (unsigned short*)(smem + 16384);
  unsigned short* PsB = (unsigned short*)(smem + 32768);

  const int tid = threadIdx.x, lane = tid & 63, wid = tid >> 6;
  const int g = wid >> 2, w = wid & 3;
  const int b = blockIdx.y >> 3, h = blockIdx.y & 7;
  const int q0 = blockIdx.x * 64 + w * 16;
  const int rq = lane & 15, lg = lane >> 4, kk8 = lg * 8;

  unsigned short* Ksg = KsB + g * 4096;
  unsigned short* Vsg = VsB + g * 4096;
  unsigned short* Psw = PsB + wid * (16 * LDPS);

  const unsigned short* Qb = Qp + ((size_t)b * Sc) * Dc + h * DKc;
  const unsigned short* Kb = Kp + ((size_t)b * Sc) * Dc + h * DKc;
  const unsigned short* Vh = Vtp + ((size_t)b * Dc + h * DKc) * Sc;

  // Q as B-fragment: col = lane&15 = q-local, k = (lane>>4)*8+j
  short8 qa[2];
#pragma unroll
  for (int c = 0; c < 2; ++c)
    qa[c] = *(const short8*)(Qb + (size_t)(q0 + rq) * Dc + c * 32 + kk8);

  floatx4 o_acc[4] = {};
  floatx4 acc_l = {};
  float m_run = -1e30f;  // log2-domain running max, per-lane q = lane&15

  short8 ones;
#pragma unroll
  for (int j = 0; j < 8; ++j) ones[j] = (short)0x3F80;

  const float C2 = 0.18033688f;  // (1/sqrt(64)) * log2(e)

  // staging: 256 threads/group stage K[64][64] + V^T[64][64], XOR swizzle
  const int u = tid & 255;
  const int sr = u >> 2, sc16 = (u & 3) * 16;
  const int st0 = (sr * 64 + sc16) ^ ((sr & 7) << 3);
  const int st1 = (sr * 64 + sc16 + 8) ^ ((sr & 7) << 3);

  for (int it = 0; it < 32; ++it) {
    const int k0 = g * (Sc / 2) + it * 64;
    {
      const unsigned short* ks = Kb + (size_t)(k0 + sr) * Dc + sc16;
      *(short8*)&Ksg[st0] = *(const short8*)ks;
      *(short8*)&Ksg[st1] = *(const short8*)(ks + 8);
      const unsigned short* vs = Vh + (size_t)sr * Sc + k0 + sc16;
      *(short8*)&Vsg[st0] = *(const short8*)vs;
      *(short8*)&Vsg[st1] = *(const short8*)(vs + 8);
    }
    __syncthreads();

    // QK^T (swapped): s4[kt][j] = S^T[key = kt*16+lg*4+j][q = rq]
    floatx4 s4[4] = {};
#pragma unroll
    for (int kt = 0; kt < 4; ++kt) {
      const int row = kt * 16 + rq, sx = (rq & 7) << 3;
      short8 a0 = *(const short8*)&Ksg[(row * 64 + kk8) ^ sx];
      short8 a1 = *(const short8*)&Ksg[(row * 64 + 32 + kk8) ^ sx];
      s4[kt] = __builtin_amdgcn_mfma_f32_16x16x32_bf16(a0, qa[0], s4[kt], 0, 0, 0);
      s4[kt] = __builtin_amdgcn_mfma_f32_16x16x32_bf16(a1, qa[1], s4[kt], 0, 0, 0);
    }
    // row max: 15 local fmax + 2 shfl
    float t01 = fmaxf(fmaxf(s4[0][0], s4[0][1]), fmaxf(s4[0][2], s4[0][3]));
    float t23 = fmaxf(fmaxf(s4[1][0], s4[1][1]), fmaxf(s4[1][2], s4[1][3]));
    float t45 = fmaxf(fmaxf(s4[2][0], s4[2][1]), fmaxf(s4[2][2], s4[2][3]));
    float t67 = fmaxf(fmaxf(s4[3][0], s4[3][1]), fmaxf(s4[3][2], s4[3][3]));
    float tm = fmaxf(fmaxf(t01, t23), fmaxf(t45, t67)) * C2;
    tm = fmaxf(tm, __shfl_xor(tm, 16, 64));
    tm = fmaxf(tm, __shfl_xor(tm, 32, 64));

    if (__any(tm > m_run)) {
      float mn = fmaxf(m_run, tm);
      float scf = exp2_fast(m_run - mn);
      m_run = mn;
      float sc_c[4];
#pragma unroll
      for (int j = 0; j < 4; ++j) sc_c[j] = __shfl(scf, lg * 4 + j, 64);
#pragma unroll
      for (int j = 0; j < 4; ++j) {
        acc_l[j] *= sc_c[j];
#pragma unroll
        for (int dt = 0; dt < 4; ++dt) o_acc[dt][j] *= sc_c[j];
      }
    }

    // P = 2^(s*C2 - m): hardware cvt_pk pack, 4x b64 stores
    const float lm = m_run;
#pragma unroll
    for (int kt = 0; kt < 4; ++kt) {
      float p0 = exp2_fast(fmaf(s4[kt][0], C2, -lm));
      float p1 = exp2_fast(fmaf(s4[kt][1], C2, -lm));
      float p2 = exp2_fast(fmaf(s4[kt][2], C2, -lm));
      float p3 = exp2_fast(fmaf(s4[kt][3], C2, -lm));
      unsigned long long pv =
          (unsigned long long)cvt_pk_bf16(p0, p1) |
          ((unsigned long long)cvt_pk_bf16(p2, p3) << 32);
      *(unsigned long long*)&Psw[rq * LDPS + kt * 16 + lg * 4] = pv;
    }

    // PV: A = P rows (wave-private), B = V^T rows (swizzled)
    short8 pa0 = *(const short8*)&Psw[rq * LDPS + kk8];
    short8 pa1 = *(const short8*)&Psw[rq * LDPS + 32 + kk8];
#pragma unroll
    for (int dt = 0; dt < 4; ++dt) {
      const int vrow = dt * 16 + rq, vx = (rq & 7) << 3;
      short8 v0 = *(const short8*)&Vsg[(vrow * 64 + kk8) ^ vx];
      short8 v1 = *(const short8*)&Vsg[(vrow * 64 + 32 + kk8) ^ vx];
      o_acc[dt] = __builtin_amdgcn_mfma_f32_16x16x32_bf16(pa0, v0, o_acc[dt], 0, 0, 0);
      o_acc[dt] = __builtin_amdgcn_mfma_f32_16x16x32_bf16(pa1, v1, o_acc[dt], 0, 0, 0);
    }
    acc_l = __builtin_amdgcn_mfma_f32_16x16x32_bf16(pa0, ones, acc_l, 0, 0, 0);
    acc_l = __builtin_amdgcn_mfma_f32_16x16x32_bf16(pa1, ones, acc_l, 0, 0, 0);
    __syncthreads();
  }

  // ---- merge the two key-halves ----
  float* MO = (float*)smem;            // [64][64] f32
  float* ML = (float*)(smem + 32768);  // [64][2]
  if (g == 1) {
#pragma unroll
    for (int j = 0; j < 4; ++j) {
      int row = w * 16 + lg * 4 + j;
      if (rq == 0) ML[row * 2 + 1] = acc_l[j];
#pragma unroll
      for (int dt = 0; dt < 4; ++dt)
        MO[(size_t)row * 64 + dt * 16 + rq] = o_acc[dt][j];
    }
    if (lg == 0) ML[(w * 16 + rq) * 2] = m_run;
  }
  __syncthreads();
  if (g == 0) {
    float m0c[4];
#pragma unroll
    for (int j = 0; j < 4; ++j) m0c[j] = __shfl(m_run, lg * 4 + j, 64);
#pragma unroll
    for (int j = 0; j < 4; ++j) {
      int row = w * 16 + lg * 4 + j;
      int r = q0 + lg * 4 + j;
      float m1 = ML[row * 2 + 0], l1 = ML[row * 2 + 1];
      float m0 = m0c[j], l0 = acc_l[j];
      float mx = fmaxf(m0, m1);
      float a0 = exp2_fast(m0 - mx), a1 = exp2_fast(m1 - mx);
      float inv = 1.0f / (l0 * a0 + l1 * a1);
#pragma unroll
      for (int dt = 0; dt < 4; ++dt) {
        float o = (o_acc[dt][j] * a0 + MO[(size_t)row * 64 + dt * 16 + rq] * a1) * inv;
        Op[((size_t)b * Sc + r) * Dc + h * DKc + dt * 16 + rq] = f2bf(o);
      }
    }
  }
}

// ---------------- launcher --------------------------------------------------
extern "C" void kernel_launch(void* const* d_in, const int* in_sizes, int n_in,
                              void* d_out, int out_size, void* d_ws, size_t ws_size,
                              hipStream_t stream) {
  const float* q_in = (const float*)d_in[0];
  const float* k_in = (const float*)d_in[1];
  const float* v_in = (const float*)d_in[2];
  const float* Wq = (const float*)d_in[3];
  const float* Wk = (const float*)d_in[4];
  const float* Wv = (const float*)d_in[5];
  const float* Wo = (const float*)d_in[6];

  unsigned short* wq_b = (unsigned short*)d_ws;
  unsigned short* wk_b = wq_b + Dc * Dc;
  unsigned short* wv_b = wk_b + Dc * Dc;
  unsigned short* wo_b = wv_b + Dc * Dc;
  unsigned short* qb = wo_b + Dc * Dc;
  unsigned short* kb = qb + (size_t)Mc * Dc;
  unsigned short* vb = kb + (size_t)Mc * Dc;
  unsigned short* ab = vb + (size_t)Mc * Dc;
  unsigned short* vt = ab + (size_t)Mc * Dc;  // V^T per (b): [D][S]

  dim3 cg(Dc * Dc / 4 / 256, 4);
  cast_w<<<cg, 256, 0, stream>>>(Wq, Wk, Wv, Wo, wq_b);

  dim3 gg(Dc / 64, Mc / 128);  // (8, 64) = 512 blocks
  gemm_bt<1, 0><<<gg, 256, 0, stream>>>(q_in, wq_b, qb, Mc, Dc, Dc);
  gemm_bt<1, 0><<<gg, 256, 0, stream>>>(k_in, wk_b, kb, Mc, Dc, Dc);
  gemm_bt<1, 0><<<gg, 256, 0, stream>>>(v_in, wv_b, vb, Mc, Dc, Dc);

  dim3 tg(Sc / 64, Dc / 64, Bc);
  transpose_v<<<tg, 256, 0, stream>>>(vb, vt);

  dim3 ga(Sc / 64, Bc * Hc);  // (64, 16) = 1024 blocks, 512 thr
  attn_fwd<<<ga, 512, 0, stream>>>(qb, kb, vt, ab);

  gemm_bt<0, 1><<<gg, 256, 0, stream>>>(ab, wo_b, (float*)d_out, Mc, Dc, Dc);
}

// Round 8
// 217.887 us; speedup vs baseline: 1.0228x; 1.0228x over previous
//
#include <hip/hip_runtime.h>
#include <hip/hip_bf16.h>

typedef short short8 __attribute__((ext_vector_type(8)));
typedef short short4v __attribute__((ext_vector_type(4)));
typedef float floatx4 __attribute__((ext_vector_type(4)));
typedef unsigned int uint4v __attribute__((ext_vector_type(4)));

constexpr int Bc = 2, Sc = 4096, Dc = 512, Hc = 8, DKc = 64;
constexpr int Mc = Bc * Sc;  // 8192

static __device__ __forceinline__ unsigned short f2bf(float f) {
  unsigned int u = __builtin_bit_cast(unsigned int, f);
  unsigned int rb = ((u >> 16) & 1u) + 0x7fffu;
  return (unsigned short)((u + rb) >> 16);
}
// hardware packed f32x2 -> bf16x2 (RNE), 1 instruction
static __device__ __forceinline__ unsigned int cvt_pk_bf16(float lo, float hi) {
  unsigned int r;
  asm("v_cvt_pk_bf16_f32 %0, %1, %2" : "=v"(r) : "v"(lo), "v"(hi));
  return r;
}
// 2^x, 1 instruction
static __device__ __forceinline__ float exp2_fast(float x) {
  float r;
  asm("v_exp_f32 %0, %1" : "=v"(r) : "v"(x));
  return r;
}

// ---------------- weight cast ------------------------------------------------
__global__ __launch_bounds__(256) void cast_w(
    const float* __restrict__ a, const float* __restrict__ b,
    const float* __restrict__ c, const float* __restrict__ d,
    unsigned short* __restrict__ out) {
  const float* srcs[4] = {a, b, c, d};
  const int m = blockIdx.y;
  const int i = (blockIdx.x * 256 + threadIdx.x) * 4;
  float4 v = *(const float4*)(srcs[m] + i);
  unsigned short t4[4] = {f2bf(v.x), f2bf(v.y), f2bf(v.z), f2bf(v.w)};
  *(short4v*)(out + (size_t)m * (Dc * Dc) + i) = *(short4v*)t4;
}

// ---------------- GEMM: Y[M,N] = X[M,K] @ W[N,K]^T ---------------------------
template <int IN_F32, int OUT_F32>
__global__ __launch_bounds__(256) void gemm_bt(
    const void* __restrict__ Xv, const unsigned short* __restrict__ Wb,
    void* __restrict__ Yv, int Mdim, int N, int K) {
  constexpr int BM = 128, BN = 64, BK = 32, LDP = 40;
  __shared__ unsigned short As[BM * LDP];
  __shared__ unsigned short Bs[BN * LDP];
  const int tid = threadIdx.x;
  const int lane = tid & 63, wid = tid >> 6;
  const int wm = wid >> 1, wn = wid & 1;
  const int bm = blockIdx.y * BM, bn = blockIdx.x * BN;
  const int rq = lane & 15, kk8 = (lane >> 4) * 8;
  const int sr = tid >> 1, sc = (tid & 1) * 16;
  const int brow = tid >> 2, bc8 = (tid & 3) * 8;

  floatx4 acc[4][2] = {};

  for (int k0 = 0; k0 < K; k0 += BK) {
    if (IN_F32) {
      const float* src = (const float*)Xv + (size_t)(bm + sr) * K + k0 + sc;
      unsigned int t2[8];
#pragma unroll
      for (int i = 0; i < 4; ++i) {
        float4 v = *(const float4*)(src + i * 4);
        t2[i * 2 + 0] = cvt_pk_bf16(v.x, v.y);
        t2[i * 2 + 1] = cvt_pk_bf16(v.z, v.w);
      }
      uint4v u0 = {t2[0], t2[1], t2[2], t2[3]};
      uint4v u1 = {t2[4], t2[5], t2[6], t2[7]};
      *(uint4v*)&As[sr * LDP + sc] = u0;
      *(uint4v*)&As[sr * LDP + sc + 8] = u1;
    } else {
      const unsigned short* src =
          (const unsigned short*)Xv + (size_t)(bm + sr) * K + k0 + sc;
      *(short8*)&As[sr * LDP + sc] = *(const short8*)src;
      *(short8*)&As[sr * LDP + sc + 8] = *(const short8*)(src + 8);
    }
    *(short8*)&Bs[brow * LDP + bc8] =
        *(const short8*)(Wb + (size_t)(bn + brow) * K + k0 + bc8);
    __syncthreads();

    short8 af[4], bfr[2];
#pragma unroll
    for (int mi = 0; mi < 4; ++mi)
      af[mi] = *(const short8*)&As[(wm * 64 + mi * 16 + rq) * LDP + kk8];
#pragma unroll
    for (int ni = 0; ni < 2; ++ni)
      bfr[ni] = *(const short8*)&Bs[(wn * 32 + ni * 16 + rq) * LDP + kk8];
#pragma unroll
    for (int mi = 0; mi < 4; ++mi)
#pragma unroll
      for (int ni = 0; ni < 2; ++ni)
        acc[mi][ni] = __builtin_amdgcn_mfma_f32_16x16x32_bf16(
            af[mi], bfr[ni], acc[mi][ni], 0, 0, 0);
    __syncthreads();
  }

#pragma unroll
  for (int mi = 0; mi < 4; ++mi)
#pragma unroll
    for (int ni = 0; ni < 2; ++ni)
#pragma unroll
      for (int j = 0; j < 4; ++j) {
        int r = bm + wm * 64 + mi * 16 + (lane >> 4) * 4 + j;
        int c = bn + wn * 32 + ni * 16 + rq;
        float v = acc[mi][ni][j];
        if (OUT_F32)
          ((float*)Yv)[(size_t)r * N + c] = v;
        else
          ((unsigned short*)Yv)[(size_t)r * N + c] = f2bf(v);
      }
}

// ---------------- V transpose: vt[b][c][s] = vb[b][s][c] ---------------------
__global__ __launch_bounds__(256) void transpose_v(
    const unsigned short* __restrict__ vb, unsigned short* __restrict__ vt) {
  constexpr int LDT = 65;
  __shared__ unsigned short T[64 * LDT];
  const int tid = threadIdx.x;
  const int s0 = blockIdx.x * 64, c0 = blockIdx.y * 64, b = blockIdx.z;
  const int r = tid >> 2, cs = (tid & 3) * 16;
  const unsigned short* src = vb + ((size_t)b * Sc + s0 + r) * Dc + c0 + cs;
  *(short8*)&T[r * LDT + cs] = *(const short8*)src;
  *(short8*)&T[r * LDT + cs + 8] = *(const short8*)(src + 8);
  __syncthreads();
  unsigned short* dst = vt + ((size_t)b * Dc + c0 + r) * Sc + s0 + cs;
  unsigned short tmp[16];
#pragma unroll
  for (int j = 0; j < 16; ++j) tmp[j] = T[(cs + j) * LDT + r];
  *(short8*)dst = *(short8*)&tmp[0];
  *(short8*)(dst + 8) = *(short8*)&tmp[8];
}

// ---------------- flash attention --------------------------------------------
// Block = 128 q-rows, 8 waves = 4 q-chunks (qc, 32q) x 2 key-halves (kh, 32k).
// One shared 64-key K/V tile per iter (no S-split) -> 14 B LDS per q*key cell
// (vs 24 in R7). Swapped QK^T; l via in-register reduce; 2-way key-half merge.
// launch_bounds (512,4): VGPR cap 128 (6 forced spills in R5 - never again).
__global__ __launch_bounds__(512, 4) void attn_fwd(
    const unsigned short* __restrict__ Qp, const unsigned short* __restrict__ Kp,
    const unsigned short* __restrict__ Vtp, unsigned short* __restrict__ Op) {
  // LDS bytes: Ks [0,8192) [64][64] swz; Vs [8192,16384) V^T same;
  // Ps [16384,36864): 8 waves x 2qi x [16 q][40] (pitch 40 elem = 80B, 16B-align)
  // Merge overlay: MO f32 [4 qc][32 q][64 dk] @0 (32KB), ML f32 [128][2] @32768.
  __shared__ unsigned char smem[36864];
  unsigned short* Ks = (unsigned short*)smem;
  unsigned short* Vs = (unsigned short*)(smem + 8192);
  unsigned short* PsB = (unsigned short*)(smem + 16384);

  const int tid = threadIdx.x, lane = tid & 63, wid = tid >> 6;
  const int qc = wid >> 1, kh = wid & 1;
  const int b = blockIdx.y >> 3, h = blockIdx.y & 7;
  const int q0 = blockIdx.x * 128 + qc * 32;
  const int rq = lane & 15, lg = lane >> 4, kk8 = lg * 8;

  unsigned short* Psw = PsB + wid * 1280;  // elems: 2 qi x 16 x 40

  const unsigned short* Qb = Qp + ((size_t)b * Sc) * Dc + h * DKc;
  const unsigned short* Kb = Kp + ((size_t)b * Sc) * Dc + h * DKc;
  const unsigned short* Vh = Vtp + ((size_t)b * Dc + h * DKc) * Sc;

  // Q as B-fragment: col = lane&15 = q-local, k = (lane>>4)*8+j
  short8 qa[2][2];
#pragma unroll
  for (int qi = 0; qi < 2; ++qi)
#pragma unroll
    for (int c = 0; c < 2; ++c)
      qa[qi][c] = *(const short8*)(Qb + (size_t)(q0 + qi * 16 + rq) * Dc + c * 32 + kk8);

  floatx4 o_acc[2][4] = {};
  float l_run[2] = {0.f, 0.f};
  float m_run[2] = {-1e30f, -1e30f};  // per-lane (q = lane&15), log2 domain

  const float C2 = 0.18033688f;  // (1/sqrt(64)) * log2(e)

  // staging: 512 threads stage K[64][64] + V^T[64][64], 16B each, XOR swizzle
  const int sr = tid >> 3, sc8 = (tid & 7) * 8;
  const int st = (sr * 64 + sc8) ^ ((sr & 7) << 3);
  const int sx = (rq & 7) << 3;

  for (int it = 0; it < 64; ++it) {
    const int k0 = it * 64;
    *(short8*)&Ks[st] = *(const short8*)(Kb + (size_t)(k0 + sr) * Dc + sc8);
    *(short8*)&Vs[st] = *(const short8*)(Vh + (size_t)sr * Sc + k0 + sc8);
    __syncthreads();

    // K A-frags for this wave's key-half (shared across both q-subtiles)
    short8 ka[2][2];
#pragma unroll
    for (int ks = 0; ks < 2; ++ks)
#pragma unroll
      for (int c = 0; c < 2; ++c) {
        const int row = kh * 32 + ks * 16 + rq;
        ka[ks][c] = *(const short8*)&Ks[(row * 64 + c * 32 + kk8) ^ sx];
      }

#pragma unroll
    for (int qi = 0; qi < 2; ++qi) {
      // swapped QK^T: s[ks][j] = S^T[key = kh*32+ks*16+lg*4+j][q = rq]
      floatx4 s[2] = {};
#pragma unroll
      for (int ks = 0; ks < 2; ++ks) {
        s[ks] = __builtin_amdgcn_mfma_f32_16x16x32_bf16(ka[ks][0], qa[qi][0], s[ks], 0, 0, 0);
        s[ks] = __builtin_amdgcn_mfma_f32_16x16x32_bf16(ka[ks][1], qa[qi][1], s[ks], 0, 0, 0);
      }
      // row max over the wave's 32 keys: 7 local fmax + 2 shfl
      float tm = fmaxf(fmaxf(fmaxf(s[0][0], s[0][1]), fmaxf(s[0][2], s[0][3])),
                       fmaxf(fmaxf(s[1][0], s[1][1]), fmaxf(s[1][2], s[1][3]))) * C2;
      tm = fmaxf(tm, __shfl_xor(tm, 16, 64));
      tm = fmaxf(tm, __shfl_xor(tm, 32, 64));

      if (__any(tm > m_run[qi])) {
        float mn = fmaxf(m_run[qi], tm);
        float scf = exp2_fast(m_run[qi] - mn);
        m_run[qi] = mn;
        l_run[qi] *= scf;
        float sc_c[4];
#pragma unroll
        for (int j = 0; j < 4; ++j) sc_c[j] = __shfl(scf, lg * 4 + j, 64);
#pragma unroll
        for (int j = 0; j < 4; ++j)
#pragma unroll
          for (int dt = 0; dt < 4; ++dt) o_acc[qi][dt][j] *= sc_c[j];
      }

      // P = 2^(s*C2 - m); pack via cvt_pk; l via in-register + 2-shfl reduce
      const float lm = m_run[qi];
      float lsum = 0.f;
#pragma unroll
      for (int ks = 0; ks < 2; ++ks) {
        float p0 = exp2_fast(fmaf(s[ks][0], C2, -lm));
        float p1 = exp2_fast(fmaf(s[ks][1], C2, -lm));
        float p2 = exp2_fast(fmaf(s[ks][2], C2, -lm));
        float p3 = exp2_fast(fmaf(s[ks][3], C2, -lm));
        lsum += (p0 + p1) + (p2 + p3);
        unsigned long long pv =
            (unsigned long long)cvt_pk_bf16(p0, p1) |
            ((unsigned long long)cvt_pk_bf16(p2, p3) << 32);
        *(unsigned long long*)&Psw[qi * 640 + rq * 40 + ks * 16 + lg * 4] = pv;
      }
      lsum += __shfl_xor(lsum, 16, 64);
      lsum += __shfl_xor(lsum, 32, 64);
      l_run[qi] += lsum;
    }

    // PV: A = P rows (wave-private), B = V^T rows, K=32 = wave's key-half
    short8 pa0 = *(const short8*)&Psw[0 * 640 + rq * 40 + kk8];
    short8 pa1 = *(const short8*)&Psw[1 * 640 + rq * 40 + kk8];
#pragma unroll
    for (int dt = 0; dt < 4; ++dt) {
      const int vrow = dt * 16 + rq;
      short8 v = *(const short8*)&Vs[(vrow * 64 + kh * 32 + kk8) ^ sx];
      o_acc[0][dt] = __builtin_amdgcn_mfma_f32_16x16x32_bf16(pa0, v, o_acc[0][dt], 0, 0, 0);
      o_acc[1][dt] = __builtin_amdgcn_mfma_f32_16x16x32_bf16(pa1, v, o_acc[1][dt], 0, 0, 0);
    }
    __syncthreads();
  }

  // ---- 2-way key-half merge (kh=1 publishes, kh=0 combines + writes) ----
  float* MO = (float*)smem;            // [4 qc][32 q][64 dk]
  float* ML = (float*)(smem + 32768);  // [128 q][2] {m, l}
  if (kh == 1) {
#pragma unroll
    for (int qi = 0; qi < 2; ++qi) {
#pragma unroll
      for (int j = 0; j < 4; ++j) {
        int row = qc * 32 + qi * 16 + lg * 4 + j;
#pragma unroll
        for (int dt = 0; dt < 4; ++dt)
          MO[(size_t)row * 64 + dt * 16 + rq] = o_acc[qi][dt][j];
      }
      if (lg == 0) {
        int row = qc * 32 + qi * 16 + rq;
        ML[row * 2 + 0] = m_run[qi];
        ML[row * 2 + 1] = l_run[qi];
      }
    }
  }
  __syncthreads();
  if (kh == 0) {
#pragma unroll
    for (int qi = 0; qi < 2; ++qi) {
      float m0c[4], l0c[4];
#pragma unroll
      for (int j = 0; j < 4; ++j) {
        m0c[j] = __shfl(m_run[qi], lg * 4 + j, 64);
        l0c[j] = __shfl(l_run[qi], lg * 4 + j, 64);
      }
#pragma unroll
      for (int j = 0; j < 4; ++j) {
        int row = qc * 32 + qi * 16 + lg * 4 + j;
        int r = q0 + qi * 16 + lg * 4 + j;
        float m1 = ML[row * 2 + 0], l1 = ML[row * 2 + 1];
        float mx = fmaxf(m0c[j], m1);
        float a0 = exp2_fast(m0c[j] - mx), a1 = exp2_fast(m1 - mx);
        float inv = 1.0f / (l0c[j] * a0 + l1 * a1);
#pragma unroll
        for (int dt = 0; dt < 4; ++dt) {
          float o = (o_acc[qi][dt][j] * a0 + MO[(size_t)row * 64 + dt * 16 + rq] * a1) * inv;
          Op[((size_t)b * Sc + r) * Dc + h * DKc + dt * 16 + rq] = f2bf(o);
        }
      }
    }
  }
}

// ---------------- launcher --------------------------------------------------
extern "C" void kernel_launch(void* const* d_in, const int* in_sizes, int n_in,
                              void* d_out, int out_size, void* d_ws, size_t ws_size,
                              hipStream_t stream) {
  const float* q_in = (const float*)d_in[0];
  const float* k_in = (const float*)d_in[1];
  const float* v_in = (const float*)d_in[2];
  const float* Wq = (const float*)d_in[3];
  const float* Wk = (const float*)d_in[4];
  const float* Wv = (const float*)d_in[5];
  const float* Wo = (const float*)d_in[6];

  unsigned short* wq_b = (unsigned short*)d_ws;
  unsigned short* wk_b = wq_b + Dc * Dc;
  unsigned short* wv_b = wk_b + Dc * Dc;
  unsigned short* wo_b = wv_b + Dc * Dc;
  unsigned short* qb = wo_b + Dc * Dc;
  unsigned short* kb = qb + (size_t)Mc * Dc;
  unsigned short* vb = kb + (size_t)Mc * Dc;
  unsigned short* ab = vb + (size_t)Mc * Dc;
  unsigned short* vt = ab + (size_t)Mc * Dc;  // V^T per (b): [D][S]

  dim3 cg(Dc * Dc / 4 / 256, 4);
  cast_w<<<cg, 256, 0, stream>>>(Wq, Wk, Wv, Wo, wq_b);

  dim3 gg(Dc / 64, Mc / 128);  // (8, 64) = 512 blocks
  gemm_bt<1, 0><<<gg, 256, 0, stream>>>(q_in, wq_b, qb, Mc, Dc, Dc);
  gemm_bt<1, 0><<<gg, 256, 0, stream>>>(k_in, wk_b, kb, Mc, Dc, Dc);
  gemm_bt<1, 0><<<gg, 256, 0, stream>>>(v_in, wv_b, vb, Mc, Dc, Dc);

  dim3 tg(Sc / 64, Dc / 64, Bc);
  transpose_v<<<tg, 256, 0, stream>>>(vb, vt);

  dim3 ga(Sc / 128, Bc * Hc);  // (32, 16) = 512 blocks, 512 thr
  attn_fwd<<<ga, 512, 0, stream>>>(qb, kb, vt, ab);

  gemm_bt<0, 1><<<gg, 256, 0, stream>>>(ab, wo_b, (float*)d_out, Mc, Dc, Dc);
}

// Round 12
// 193.882 us; speedup vs baseline: 1.1494x; 1.1238x over previous
//
#include <hip/hip_runtime.h>
#include <hip/hip_bf16.h>

typedef short short8 __attribute__((ext_vector_type(8)));
typedef short short4v __attribute__((ext_vector_type(4)));
typedef float floatx4 __attribute__((ext_vector_type(4)));
typedef unsigned int uint4v __attribute__((ext_vector_type(4)));

constexpr int Bc = 2, Sc = 4096, Dc = 512, Hc = 8, DKc = 64;
constexpr int Mc = Bc * Sc;  // 8192

static __device__ __forceinline__ unsigned short f2bf(float f) {
  unsigned int u = __builtin_bit_cast(unsigned int, f);
  unsigned int rb = ((u >> 16) & 1u) + 0x7fffu;
  return (unsigned short)((u + rb) >> 16);
}
// hardware packed f32x2 -> bf16x2 (RNE), 1 instruction
static __device__ __forceinline__ unsigned int cvt_pk_bf16(float lo, float hi) {
  unsigned int r;
  asm("v_cvt_pk_bf16_f32 %0, %1, %2" : "=v"(r) : "v"(lo), "v"(hi));
  return r;
}
// 2^x, 1 instruction
static __device__ __forceinline__ float exp2_fast(float x) {
  float r;
  asm("v_exp_f32 %0, %1" : "=v"(r) : "v"(x));
  return r;
}
// NOTE (R9-R11 lesson): v_permlane16/32_swap_b32 is BANNED this session.
// Three correctness failures (absmax .07-1.15) with desk-checked semantics;
// the hardware behavior does not match any documented model I derived.
// Cross-lane ops here use only __shfl_xor (verified PASS in R4-R8).

// ---------------- weight cast ------------------------------------------------
__global__ __launch_bounds__(256) void cast_w(
    const float* __restrict__ a, const float* __restrict__ b,
    const float* __restrict__ c, const float* __restrict__ d,
    unsigned short* __restrict__ out) {
  const float* srcs[4] = {a, b, c, d};
  const int m = blockIdx.y;
  const int i = (blockIdx.x * 256 + threadIdx.x) * 4;
  float4 v = *(const float4*)(srcs[m] + i);
  unsigned short t4[4] = {f2bf(v.x), f2bf(v.y), f2bf(v.z), f2bf(v.w)};
  *(short4v*)(out + (size_t)m * (Dc * Dc) + i) = *(short4v*)t4;
}

// ---------------- GEMM: Y[M,N] = X[M,K] @ W[N,K]^T ---------------------------
template <int IN_F32, int OUT_F32>
__global__ __launch_bounds__(256) void gemm_bt(
    const void* __restrict__ Xv, const unsigned short* __restrict__ Wb,
    void* __restrict__ Yv, int Mdim, int N, int K) {
  constexpr int BM = 128, BN = 64, BK = 32, LDP = 40;
  __shared__ unsigned short As[BM * LDP];
  __shared__ unsigned short Bs[BN * LDP];
  const int tid = threadIdx.x;
  const int lane = tid & 63, wid = tid >> 6;
  const int wm = wid >> 1, wn = wid & 1;
  const int bm = blockIdx.y * BM, bn = blockIdx.x * BN;
  const int rq = lane & 15, kk8 = (lane >> 4) * 8;
  const int sr = tid >> 1, sc = (tid & 1) * 16;
  const int brow = tid >> 2, bc8 = (tid & 3) * 8;

  floatx4 acc[4][2] = {};

  for (int k0 = 0; k0 < K; k0 += BK) {
    if (IN_F32) {
      const float* src = (const float*)Xv + (size_t)(bm + sr) * K + k0 + sc;
      unsigned int t2[8];
#pragma unroll
      for (int i = 0; i < 4; ++i) {
        float4 v = *(const float4*)(src + i * 4);
        t2[i * 2 + 0] = cvt_pk_bf16(v.x, v.y);
        t2[i * 2 + 1] = cvt_pk_bf16(v.z, v.w);
      }
      uint4v u0 = {t2[0], t2[1], t2[2], t2[3]};
      uint4v u1 = {t2[4], t2[5], t2[6], t2[7]};
      *(uint4v*)&As[sr * LDP + sc] = u0;
      *(uint4v*)&As[sr * LDP + sc + 8] = u1;
    } else {
      const unsigned short* src =
          (const unsigned short*)Xv + (size_t)(bm + sr) * K + k0 + sc;
      *(short8*)&As[sr * LDP + sc] = *(const short8*)src;
      *(short8*)&As[sr * LDP + sc + 8] = *(const short8*)(src + 8);
    }
    *(short8*)&Bs[brow * LDP + bc8] =
        *(const short8*)(Wb + (size_t)(bn + brow) * K + k0 + bc8);
    __syncthreads();

    short8 af[4], bfr[2];
#pragma unroll
    for (int mi = 0; mi < 4; ++mi)
      af[mi] = *(const short8*)&As[(wm * 64 + mi * 16 + rq) * LDP + kk8];
#pragma unroll
    for (int ni = 0; ni < 2; ++ni)
      bfr[ni] = *(const short8*)&Bs[(wn * 32 + ni * 16 + rq) * LDP + kk8];
#pragma unroll
    for (int mi = 0; mi < 4; ++mi)
#pragma unroll
      for (int ni = 0; ni < 2; ++ni)
        acc[mi][ni] = __builtin_amdgcn_mfma_f32_16x16x32_bf16(
            af[mi], bfr[ni], acc[mi][ni], 0, 0, 0);
    __syncthreads();
  }

#pragma unroll
  for (int mi = 0; mi < 4; ++mi)
#pragma unroll
    for (int ni = 0; ni < 2; ++ni)
#pragma unroll
      for (int j = 0; j < 4; ++j) {
        int r = bm + wm * 64 + mi * 16 + (lane >> 4) * 4 + j;
        int c = bn + wn * 32 + ni * 16 + rq;
        float v = acc[mi][ni][j];
        if (OUT_F32)
          ((float*)Yv)[(size_t)r * N + c] = v;
        else
          ((unsigned short*)Yv)[(size_t)r * N + c] = f2bf(v);
      }
}

// ---------------- V transpose: vt[b][c][s] = vb[b][s][c] ---------------------
__global__ __launch_bounds__(256) void transpose_v(
    const unsigned short* __restrict__ vb, unsigned short* __restrict__ vt) {
  constexpr int LDT = 65;
  __shared__ unsigned short T[64 * LDT];
  const int tid = threadIdx.x;
  const int s0 = blockIdx.x * 64, c0 = blockIdx.y * 64, b = blockIdx.z;
  const int r = tid >> 2, cs = (tid & 3) * 16;
  const unsigned short* src = vb + ((size_t)b * Sc + s0 + r) * Dc + c0 + cs;
  *(short8*)&T[r * LDT + cs] = *(const short8*)src;
  *(short8*)&T[r * LDT + cs + 8] = *(const short8*)(src + 8);
  __syncthreads();
  unsigned short* dst = vt + ((size_t)b * Dc + c0 + r) * Sc + s0 + cs;
  unsigned short tmp[16];
#pragma unroll
  for (int j = 0; j < 16; ++j) tmp[j] = T[(cs + j) * LDT + r];
  *(short8*)dst = *(short8*)&tmp[0];
  *(short8*)(dst + 8) = *(short8*)&tmp[8];
}

// ---------------- flash attention --------------------------------------------
// Block = 128 q-rows, 8 waves = 4 q-chunks (qc, 32q) x 2 key-halves (kh, 32k).
// One shared 64-key K/V tile per iter -> 14 B LDS per q*key cell.
// Softmax common path has ZERO cross-lane ops:
//  - defer-max (T13, THR=8 in log2 domain): per-lane partial max checked via
//    __any; full shfl reduce + rescale only when the bound would be exceeded.
//    P <= 2^8; bf16 rel error is scale-invariant -> precision-neutral.
//  - deferred l-reduction: per-lane partial sums (own 8 keys), rescaled by the
//    replicated per-q scf, cross-lane reduced ONCE after the loop.
// launch_bounds (512,4): VGPR cap 128 (R5: tighter cap => scratch spill).
__global__ __launch_bounds__(512, 4) void attn_fwd(
    const unsigned short* __restrict__ Qp, const unsigned short* __restrict__ Kp,
    const unsigned short* __restrict__ Vtp, unsigned short* __restrict__ Op) {
  // LDS bytes: Ks [0,8192) [64][64] swz; Vs [8192,16384) V^T same;
  // Ps [16384,36864): 8 waves x 2qi x [16 q][40] (pitch 40 elem = 80B)
  // Merge overlay: MO f32 [4 qc][32 q][64 dk] @0 (32KB), ML f32 [128][2] @32768.
  __shared__ unsigned char smem[36864];
  unsigned short* Ks = (unsigned short*)smem;
  unsigned short* Vs = (unsigned short*)(smem + 8192);
  unsigned short* PsB = (unsigned short*)(smem + 16384);

  const int tid = threadIdx.x, lane = tid & 63, wid = tid >> 6;
  const int qc = wid >> 1, kh = wid & 1;
  const int b = blockIdx.y >> 3, h = blockIdx.y & 7;
  const int q0 = blockIdx.x * 128 + qc * 32;
  const int rq = lane & 15, lg = lane >> 4, kk8 = lg * 8;

  unsigned short* Psw = PsB + wid * 1280;  // elems: 2 qi x 16 x 40

  const unsigned short* Qb = Qp + ((size_t)b * Sc) * Dc + h * DKc;
  const unsigned short* Kb = Kp + ((size_t)b * Sc) * Dc + h * DKc;
  const unsigned short* Vh = Vtp + ((size_t)b * Dc + h * DKc) * Sc;

  // Q as B-fragment: col = lane&15 = q-local, k = (lane>>4)*8+j
  short8 qa[2][2];
#pragma unroll
  for (int qi = 0; qi < 2; ++qi)
#pragma unroll
    for (int c = 0; c < 2; ++c)
      qa[qi][c] = *(const short8*)(Qb + (size_t)(q0 + qi * 16 + rq) * Dc + c * 32 + kk8);

  floatx4 o_acc[2][4] = {};
  float l_part[2] = {0.f, 0.f};       // per-lane PARTIAL sum (own 8 keys)
  float m_run[2] = {-1e30f, -1e30f};  // per-lane (q = lane&15), log2 domain

  const float C2 = 0.18033688f;   // (1/sqrt(64)) * log2(e)
  const float THR = 8.0f;         // defer-max bound: P <= 2^8

  // staging: 512 threads stage K[64][64] + V^T[64][64], 16B each, XOR swizzle
  const int sr = tid >> 3, sc8 = (tid & 7) * 8;
  const int st = (sr * 64 + sc8) ^ ((sr & 7) << 3);
  const int sx = (rq & 7) << 3;

  for (int it = 0; it < 64; ++it) {
    const int k0 = it * 64;
    *(short8*)&Ks[st] = *(const short8*)(Kb + (size_t)(k0 + sr) * Dc + sc8);
    *(short8*)&Vs[st] = *(const short8*)(Vh + (size_t)sr * Sc + k0 + sc8);
    __syncthreads();

    // K A-frags for this wave's key-half (shared across both q-subtiles)
    short8 ka[2][2];
#pragma unroll
    for (int ks = 0; ks < 2; ++ks)
#pragma unroll
      for (int c = 0; c < 2; ++c) {
        const int row = kh * 32 + ks * 16 + rq;
        ka[ks][c] = *(const short8*)&Ks[(row * 64 + c * 32 + kk8) ^ sx];
      }

#pragma unroll
    for (int qi = 0; qi < 2; ++qi) {
      // swapped QK^T: s[ks][j] = S^T[key = kh*32+ks*16+lg*4+j][q = rq]
      floatx4 s[2] = {};
#pragma unroll
      for (int ks = 0; ks < 2; ++ks) {
        s[ks] = __builtin_amdgcn_mfma_f32_16x16x32_bf16(ka[ks][0], qa[qi][0], s[ks], 0, 0, 0);
        s[ks] = __builtin_amdgcn_mfma_f32_16x16x32_bf16(ka[ks][1], qa[qi][1], s[ks], 0, 0, 0);
      }
      // per-lane partial max over own 8 keys (no cross-lane on common path)
      float tp = fmaxf(fmaxf(fmaxf(s[0][0], s[0][1]), fmaxf(s[0][2], s[0][3])),
                       fmaxf(fmaxf(s[1][0], s[1][1]), fmaxf(s[1][2], s[1][3]))) * C2;

      if (__any(tp > m_run[qi] + THR)) {  // rare: bound would be exceeded
        // full row max via shfl (slow path)
        float tm = tp;
        tm = fmaxf(tm, __shfl_xor(tm, 16, 64));
        tm = fmaxf(tm, __shfl_xor(tm, 32, 64));
        if (__any(tm > m_run[qi])) {
          float mn = fmaxf(m_run[qi], tm);
          float scf = exp2_fast(m_run[qi] - mn);
          m_run[qi] = mn;
          l_part[qi] *= scf;  // partial sums rescale per-lane (scf per-q)
          float sc_c[4];
#pragma unroll
          for (int j = 0; j < 4; ++j) sc_c[j] = __shfl(scf, lg * 4 + j, 64);
#pragma unroll
          for (int j = 0; j < 4; ++j)
#pragma unroll
            for (int dt = 0; dt < 4; ++dt) o_acc[qi][dt][j] *= sc_c[j];
        }
      }

      // P = 2^(s*C2 - m); pack via cvt_pk; accumulate PARTIAL l per-lane
      const float lm = m_run[qi];
#pragma unroll
      for (int ks = 0; ks < 2; ++ks) {
        float p0 = exp2_fast(fmaf(s[ks][0], C2, -lm));
        float p1 = exp2_fast(fmaf(s[ks][1], C2, -lm));
        float p2 = exp2_fast(fmaf(s[ks][2], C2, -lm));
        float p3 = exp2_fast(fmaf(s[ks][3], C2, -lm));
        l_part[qi] += (p0 + p1) + (p2 + p3);
        unsigned long long pv =
            (unsigned long long)cvt_pk_bf16(p0, p1) |
            ((unsigned long long)cvt_pk_bf16(p2, p3) << 32);
        *(unsigned long long*)&Psw[qi * 640 + rq * 40 + ks * 16 + lg * 4] = pv;
      }
    }

    // PV: A = P rows (wave-private), B = V^T rows, K=32 = wave's key-half
    short8 pa0 = *(const short8*)&Psw[0 * 640 + rq * 40 + kk8];
    short8 pa1 = *(const short8*)&Psw[1 * 640 + rq * 40 + kk8];
#pragma unroll
    for (int dt = 0; dt < 4; ++dt) {
      const int vrow = dt * 16 + rq;
      short8 v = *(const short8*)&Vs[(vrow * 64 + kh * 32 + kk8) ^ sx];
      o_acc[0][dt] = __builtin_amdgcn_mfma_f32_16x16x32_bf16(pa0, v, o_acc[0][dt], 0, 0, 0);
      o_acc[1][dt] = __builtin_amdgcn_mfma_f32_16x16x32_bf16(pa1, v, o_acc[1][dt], 0, 0, 0);
    }
    __syncthreads();
  }

  // finalize l: one cross-lane reduce of the partial sums (2 shfls per qi)
  float l_run[2];
#pragma unroll
  for (int qi = 0; qi < 2; ++qi) {
    float ls = l_part[qi];
    ls += __shfl_xor(ls, 16, 64);
    ls += __shfl_xor(ls, 32, 64);
    l_run[qi] = ls;
  }

  // ---- 2-way key-half merge (kh=1 publishes, kh=0 combines + writes) ----
  float* MO = (float*)smem;            // [4 qc][32 q][64 dk]
  float* ML = (float*)(smem + 32768);  // [128 q][2] {m, l}
  if (kh == 1) {
#pragma unroll
    for (int qi = 0; qi < 2; ++qi) {
#pragma unroll
      for (int j = 0; j < 4; ++j) {
        int row = qc * 32 + qi * 16 + lg * 4 + j;
#pragma unroll
        for (int dt = 0; dt < 4; ++dt)
          MO[(size_t)row * 64 + dt * 16 + rq] = o_acc[qi][dt][j];
      }
      if (lg == 0) {
        int row = qc * 32 + qi * 16 + rq;
        ML[row * 2 + 0] = m_run[qi];
        ML[row * 2 + 1] = l_run[qi];
      }
    }
  }
  __syncthreads();
  if (kh == 0) {
#pragma unroll
    for (int qi = 0; qi < 2; ++qi) {
      float m0c[4], l0c[4];
#pragma unroll
      for (int j = 0; j < 4; ++j) {
        m0c[j] = __shfl(m_run[qi], lg * 4 + j, 64);
        l0c[j] = __shfl(l_run[qi], lg * 4 + j, 64);
      }
#pragma unroll
      for (int j = 0; j < 4; ++j) {
        int row = qc * 32 + qi * 16 + lg * 4 + j;
        int r = q0 + qi * 16 + lg * 4 + j;
        float m1 = ML[row * 2 + 0], l1 = ML[row * 2 + 1];
        float mx = fmaxf(m0c[j], m1);
        float a0 = exp2_fast(m0c[j] - mx), a1 = exp2_fast(m1 - mx);
        float inv = 1.0f / (l0c[j] * a0 + l1 * a1);
#pragma unroll
        for (int dt = 0; dt < 4; ++dt) {
          float o = (o_acc[qi][dt][j] * a0 + MO[(size_t)row * 64 + dt * 16 + rq] * a1) * inv;
          Op[((size_t)b * Sc + r) * Dc + h * DKc + dt * 16 + rq] = f2bf(o);
        }
      }
    }
  }
}

// ---------------- launcher --------------------------------------------------
extern "C" void kernel_launch(void* const* d_in, const int* in_sizes, int n_in,
                              void* d_out, int out_size, void* d_ws, size_t ws_size,
                              hipStream_t stream) {
  const float* q_in = (const float*)d_in[0];
  const float* k_in = (const float*)d_in[1];
  const float* v_in = (const float*)d_in[2];
  const float* Wq = (const float*)d_in[3];
  const float* Wk = (const float*)d_in[4];
  const float* Wv = (const float*)d_in[5];
  const float* Wo = (const float*)d_in[6];

  unsigned short* wq_b = (unsigned short*)d_ws;
  unsigned short* wk_b = wq_b + Dc * Dc;
  unsigned short* wv_b = wk_b + Dc * Dc;
  unsigned short* wo_b = wv_b + Dc * Dc;
  unsigned short* qb = wo_b + Dc * Dc;
  unsigned short* kb = qb + (size_t)Mc * Dc;
  unsigned short* vb = kb + (size_t)Mc * Dc;
  unsigned short* ab = vb + (size_t)Mc * Dc;
  unsigned short* vt = ab + (size_t)Mc * Dc;  // V^T per (b): [D][S]

  dim3 cg(Dc * Dc / 4 / 256, 4);
  cast_w<<<cg, 256, 0, stream>>>(Wq, Wk, Wv, Wo, wq_b);

  dim3 gg(Dc / 64, Mc / 128);  // (8, 64) = 512 blocks
  gemm_bt<1, 0><<<gg, 256, 0, stream>>>(q_in, wq_b, qb, Mc, Dc, Dc);
  gemm_bt<1, 0><<<gg, 256, 0, stream>>>(k_in, wk_b, kb, Mc, Dc, Dc);
  gemm_bt<1, 0><<<gg, 256, 0, stream>>>(v_in, wv_b, vb, Mc, Dc, Dc);

  dim3 tg(Sc / 64, Dc / 64, Bc);
  transpose_v<<<tg, 256, 0, stream>>>(vb, vt);

  dim3 ga(Sc / 128, Bc * Hc);  // (32, 16) = 512 blocks, 512 thr
  attn_fwd<<<ga, 512, 0, stream>>>(qb, kb, vt, ab);

  gemm_bt<0, 1><<<gg, 256, 0, stream>>>(ab, wo_b, (float*)d_out, Mc, Dc, Dc);
}

// Round 13
// 186.374 us; speedup vs baseline: 1.1957x; 1.0403x over previous
//
#include <hip/hip_runtime.h>
#include <hip/hip_bf16.h>

typedef short short8 __attribute__((ext_vector_type(8)));
typedef short short4v __attribute__((ext_vector_type(4)));
typedef float floatx4 __attribute__((ext_vector_type(4)));
typedef unsigned int uint4v __attribute__((ext_vector_type(4)));

constexpr int Bc = 2, Sc = 4096, Dc = 512, Hc = 8, DKc = 64;
constexpr int Mc = Bc * Sc;  // 8192

static __device__ __forceinline__ unsigned short f2bf(float f) {
  unsigned int u = __builtin_bit_cast(unsigned int, f);
  unsigned int rb = ((u >> 16) & 1u) + 0x7fffu;
  return (unsigned short)((u + rb) >> 16);
}
// hardware packed f32x2 -> bf16x2 (RNE), 1 instruction
static __device__ __forceinline__ unsigned int cvt_pk_bf16(float lo, float hi) {
  unsigned int r;
  asm("v_cvt_pk_bf16_f32 %0, %1, %2" : "=v"(r) : "v"(lo), "v"(hi));
  return r;
}
// 2^x, 1 instruction
static __device__ __forceinline__ float exp2_fast(float x) {
  float r;
  asm("v_exp_f32 %0, %1" : "=v"(r) : "v"(x));
  return r;
}
// NOTE (R9-R11 lesson): v_permlane16/32_swap_b32 is BANNED this session.
// Cross-lane ops use only __shfl_xor (verified PASS R4-R8, R12).

// ---------------- weight cast ------------------------------------------------
__global__ __launch_bounds__(256) void cast_w(
    const float* __restrict__ a, const float* __restrict__ b,
    const float* __restrict__ c, const float* __restrict__ d,
    unsigned short* __restrict__ out) {
  const float* srcs[4] = {a, b, c, d};
  const int m = blockIdx.y;
  const int i = (blockIdx.x * 256 + threadIdx.x) * 4;
  float4 v = *(const float4*)(srcs[m] + i);
  unsigned short t4[4] = {f2bf(v.x), f2bf(v.y), f2bf(v.z), f2bf(v.w)};
  *(short4v*)(out + (size_t)m * (Dc * Dc) + i) = *(short4v*)t4;
}

// ---------------- GEMM: Y[M,N] = X[M,K] @ W[N,K]^T ---------------------------
template <int IN_F32, int OUT_F32>
__global__ __launch_bounds__(256) void gemm_bt(
    const void* __restrict__ Xv, const unsigned short* __restrict__ Wb,
    void* __restrict__ Yv, int Mdim, int N, int K) {
  constexpr int BM = 128, BN = 64, BK = 32, LDP = 40;
  __shared__ unsigned short As[BM * LDP];
  __shared__ unsigned short Bs[BN * LDP];
  const int tid = threadIdx.x;
  const int lane = tid & 63, wid = tid >> 6;
  const int wm = wid >> 1, wn = wid & 1;
  const int bm = blockIdx.y * BM, bn = blockIdx.x * BN;
  const int rq = lane & 15, kk8 = (lane >> 4) * 8;
  const int sr = tid >> 1, sc = (tid & 1) * 16;
  const int brow = tid >> 2, bc8 = (tid & 3) * 8;

  floatx4 acc[4][2] = {};

  for (int k0 = 0; k0 < K; k0 += BK) {
    if (IN_F32) {
      const float* src = (const float*)Xv + (size_t)(bm + sr) * K + k0 + sc;
      unsigned int t2[8];
#pragma unroll
      for (int i = 0; i < 4; ++i) {
        float4 v = *(const float4*)(src + i * 4);
        t2[i * 2 + 0] = cvt_pk_bf16(v.x, v.y);
        t2[i * 2 + 1] = cvt_pk_bf16(v.z, v.w);
      }
      uint4v u0 = {t2[0], t2[1], t2[2], t2[3]};
      uint4v u1 = {t2[4], t2[5], t2[6], t2[7]};
      *(uint4v*)&As[sr * LDP + sc] = u0;
      *(uint4v*)&As[sr * LDP + sc + 8] = u1;
    } else {
      const unsigned short* src =
          (const unsigned short*)Xv + (size_t)(bm + sr) * K + k0 + sc;
      *(short8*)&As[sr * LDP + sc] = *(const short8*)src;
      *(short8*)&As[sr * LDP + sc + 8] = *(const short8*)(src + 8);
    }
    *(short8*)&Bs[brow * LDP + bc8] =
        *(const short8*)(Wb + (size_t)(bn + brow) * K + k0 + bc8);
    __syncthreads();

    short8 af[4], bfr[2];
#pragma unroll
    for (int mi = 0; mi < 4; ++mi)
      af[mi] = *(const short8*)&As[(wm * 64 + mi * 16 + rq) * LDP + kk8];
#pragma unroll
    for (int ni = 0; ni < 2; ++ni)
      bfr[ni] = *(const short8*)&Bs[(wn * 32 + ni * 16 + rq) * LDP + kk8];
#pragma unroll
    for (int mi = 0; mi < 4; ++mi)
#pragma unroll
      for (int ni = 0; ni < 2; ++ni)
        acc[mi][ni] = __builtin_amdgcn_mfma_f32_16x16x32_bf16(
            af[mi], bfr[ni], acc[mi][ni], 0, 0, 0);
    __syncthreads();
  }

#pragma unroll
  for (int mi = 0; mi < 4; ++mi)
#pragma unroll
    for (int ni = 0; ni < 2; ++ni)
#pragma unroll
      for (int j = 0; j < 4; ++j) {
        int r = bm + wm * 64 + mi * 16 + (lane >> 4) * 4 + j;
        int c = bn + wn * 32 + ni * 16 + rq;
        float v = acc[mi][ni][j];
        if (OUT_F32)
          ((float*)Yv)[(size_t)r * N + c] = v;
        else
          ((unsigned short*)Yv)[(size_t)r * N + c] = f2bf(v);
      }
}

// ---------------- V transpose + key-permute ---------------------------------
// vt[b][dk][s'] = vb[b][key][dk], where s' = sigma(key) permutes each aligned
// 32-key group so attn's PV A-fragment is lane-local (P never leaves the
// lane's registers). sigma(key bits [k4 k3 k2 k1 k0]) = [k3 k2 k4 k1 k0]:
//   pos = ((key>>2)&3)*8 + ((key>>4)&1)*4 + (key&3).
// attn reads vt columns linearly; the permutation makes the MFMA k-slot order
// match the slot order in which each lane natively holds its P values.
__global__ __launch_bounds__(256) void transpose_v(
    const unsigned short* __restrict__ vb, unsigned short* __restrict__ vt) {
  constexpr int LDT = 65;
  __shared__ unsigned short T[64 * LDT];
  const int tid = threadIdx.x;
  const int s0 = blockIdx.x * 64, c0 = blockIdx.y * 64, b = blockIdx.z;
  const int r = tid >> 2, cs = (tid & 3) * 16;
  const unsigned short* src = vb + ((size_t)b * Sc + s0 + r) * Dc + c0 + cs;
  *(short8*)&T[r * LDT + cs] = *(const short8*)src;
  *(short8*)&T[r * LDT + cs + 8] = *(const short8*)(src + 8);
  __syncthreads();
  unsigned short tmp[16];
#pragma unroll
  for (int j = 0; j < 16; ++j) tmp[j] = T[(cs + j) * LDT + r];
  // this thread's 16 keys are (cs..cs+15): k4 = (cs>>4)&1, k3..k0 = j.
  const int k4 = (cs >> 4) & 1;
  const int base32 = s0 + (cs & 32);
  unsigned short* dstrow = vt + ((size_t)b * Dc + c0 + r) * Sc;
#pragma unroll
  for (int g = 0; g < 4; ++g) {  // g = j>>2 = k3k2
    short4v v4 = {(short)tmp[4 * g + 0], (short)tmp[4 * g + 1],
                  (short)tmp[4 * g + 2], (short)tmp[4 * g + 3]};
    *(short4v*)(dstrow + base32 + g * 8 + k4 * 4) = v4;
  }
}

// ---------------- flash attention --------------------------------------------
// Block = 128 q-rows, 8 waves = 4 q-chunks (qc, 32q) x 2 key-halves (kh, 32k).
// Swapped QK^T; softmax common path has zero cross-lane ops (defer-max THR=8
// + deferred l-reduction, R12-verified). NEW: P stays entirely in registers —
// the sigma key-permutation (baked into vt by transpose_v) makes each lane's
// P values exactly its own PV A-fragment slots: 4 cvt_pk -> short8 -> MFMA.
// DS ops per wave-iter: 20 (R12) -> 10 (2 staging + 4 ka + 4 V-frag).
// launch_bounds (512,4): VGPR cap 128 (R5: tighter cap => scratch spill).
__global__ __launch_bounds__(512, 4) void attn_fwd(
    const unsigned short* __restrict__ Qp, const unsigned short* __restrict__ Kp,
    const unsigned short* __restrict__ Vtp, unsigned short* __restrict__ Op) {
  // LDS bytes: Ks [0,8192) [64][64] swz; Vs [8192,16384) V^T (key-permuted).
  // Merge overlay: MO f32 [128 q][64 dk] @0 (32KB), ML f32 [128][2] @32768.
  __shared__ unsigned char smem[33792];
  unsigned short* Ks = (unsigned short*)smem;
  unsigned short* Vs = (unsigned short*)(smem + 8192);

  const int tid = threadIdx.x, lane = tid & 63, wid = tid >> 6;
  const int qc = wid >> 1, kh = wid & 1;
  const int b = blockIdx.y >> 3, h = blockIdx.y & 7;
  const int q0 = blockIdx.x * 128 + qc * 32;
  const int rq = lane & 15, lg = lane >> 4, kk8 = lg * 8;

  const unsigned short* Qb = Qp + ((size_t)b * Sc) * Dc + h * DKc;
  const unsigned short* Kb = Kp + ((size_t)b * Sc) * Dc + h * DKc;
  const unsigned short* Vh = Vtp + ((size_t)b * Dc + h * DKc) * Sc;

  // Q as B-fragment: col = lane&15 = q-local, k = (lane>>4)*8+j
  short8 qa[2][2];
#pragma unroll
  for (int qi = 0; qi < 2; ++qi)
#pragma unroll
    for (int c = 0; c < 2; ++c)
      qa[qi][c] = *(const short8*)(Qb + (size_t)(q0 + qi * 16 + rq) * Dc + c * 32 + kk8);

  floatx4 o_acc[2][4] = {};
  float l_part[2] = {0.f, 0.f};       // per-lane PARTIAL sum (own 8 keys)
  float m_run[2] = {-1e30f, -1e30f};  // per-lane (q = lane&15), log2 domain

  const float C2 = 0.18033688f;   // (1/sqrt(64)) * log2(e)
  const float THR = 8.0f;         // defer-max bound: P <= 2^8

  // staging: 512 threads stage K[64][64] + V^T[64][64], 16B each, XOR swizzle
  const int sr = tid >> 3, sc8 = (tid & 7) * 8;
  const int st = (sr * 64 + sc8) ^ ((sr & 7) << 3);
  const int sx = (rq & 7) << 3;

  for (int it = 0; it < 64; ++it) {
    const int k0 = it * 64;
    *(short8*)&Ks[st] = *(const short8*)(Kb + (size_t)(k0 + sr) * Dc + sc8);
    *(short8*)&Vs[st] = *(const short8*)(Vh + (size_t)sr * Sc + k0 + sc8);
    __syncthreads();

    // K A-frags for this wave's key-half (shared across both q-subtiles)
    short8 ka[2][2];
#pragma unroll
    for (int ks = 0; ks < 2; ++ks)
#pragma unroll
      for (int c = 0; c < 2; ++c) {
        const int row = kh * 32 + ks * 16 + rq;
        ka[ks][c] = *(const short8*)&Ks[(row * 64 + c * 32 + kk8) ^ sx];
      }

    short8 pb_[2];  // per-qi PV A-frags, built fully in-register
#pragma unroll
    for (int qi = 0; qi < 2; ++qi) {
      // swapped QK^T: s[ks][j] = S^T[key = kh*32+ks*16+lg*4+j][q = rq]
      floatx4 s[2] = {};
#pragma unroll
      for (int ks = 0; ks < 2; ++ks) {
        s[ks] = __builtin_amdgcn_mfma_f32_16x16x32_bf16(ka[ks][0], qa[qi][0], s[ks], 0, 0, 0);
        s[ks] = __builtin_amdgcn_mfma_f32_16x16x32_bf16(ka[ks][1], qa[qi][1], s[ks], 0, 0, 0);
      }
      // per-lane partial max over own 8 keys (no cross-lane on common path)
      float tp = fmaxf(fmaxf(fmaxf(s[0][0], s[0][1]), fmaxf(s[0][2], s[0][3])),
                       fmaxf(fmaxf(s[1][0], s[1][1]), fmaxf(s[1][2], s[1][3]))) * C2;

      if (__any(tp > m_run[qi] + THR)) {  // rare: bound would be exceeded
        float tm = tp;
        tm = fmaxf(tm, __shfl_xor(tm, 16, 64));
        tm = fmaxf(tm, __shfl_xor(tm, 32, 64));
        if (__any(tm > m_run[qi])) {
          float mn = fmaxf(m_run[qi], tm);
          float scf = exp2_fast(m_run[qi] - mn);
          m_run[qi] = mn;
          l_part[qi] *= scf;
          float sc_c[4];
#pragma unroll
          for (int j = 0; j < 4; ++j) sc_c[j] = __shfl(scf, lg * 4 + j, 64);
#pragma unroll
          for (int j = 0; j < 4; ++j)
#pragma unroll
            for (int dt = 0; dt < 4; ++dt) o_acc[qi][dt][j] *= sc_c[j];
        }
      }

      // P = 2^(s*C2 - m), packed in A-frag slot order t = ks*4 + jj.
      // slot sigma: slot lg*8+ks*4+jj <-> key ks*16+lg*4+jj — matches the
      // key-permuted V columns, so pb_ is this lane's own A-fragment.
      const float lm = m_run[qi];
      unsigned int pw0, pw1, pw2, pw3;
      {
        float p0 = exp2_fast(fmaf(s[0][0], C2, -lm));
        float p1 = exp2_fast(fmaf(s[0][1], C2, -lm));
        float p2 = exp2_fast(fmaf(s[0][2], C2, -lm));
        float p3 = exp2_fast(fmaf(s[0][3], C2, -lm));
        l_part[qi] += (p0 + p1) + (p2 + p3);
        pw0 = cvt_pk_bf16(p0, p1);
        pw1 = cvt_pk_bf16(p2, p3);
      }
      {
        float p0 = exp2_fast(fmaf(s[1][0], C2, -lm));
        float p1 = exp2_fast(fmaf(s[1][1], C2, -lm));
        float p2 = exp2_fast(fmaf(s[1][2], C2, -lm));
        float p3 = exp2_fast(fmaf(s[1][3], C2, -lm));
        l_part[qi] += (p0 + p1) + (p2 + p3);
        pw2 = cvt_pk_bf16(p0, p1);
        pw3 = cvt_pk_bf16(p2, p3);
      }
      uint4v pw = {pw0, pw1, pw2, pw3};
      pb_[qi] = __builtin_bit_cast(short8, pw);
    }

    // PV: A = pb_ (in-register), B = key-permuted V^T rows, K=32 = key-half
#pragma unroll
    for (int dt = 0; dt < 4; ++dt) {
      const int vrow = dt * 16 + rq;
      short8 v = *(const short8*)&Vs[(vrow * 64 + kh * 32 + kk8) ^ sx];
      o_acc[0][dt] = __builtin_amdgcn_mfma_f32_16x16x32_bf16(pb_[0], v, o_acc[0][dt], 0, 0, 0);
      o_acc[1][dt] = __builtin_amdgcn_mfma_f32_16x16x32_bf16(pb_[1], v, o_acc[1][dt], 0, 0, 0);
    }
    __syncthreads();
  }

  // finalize l: one cross-lane reduce of the partial sums (2 shfls per qi)
  float l_run[2];
#pragma unroll
  for (int qi = 0; qi < 2; ++qi) {
    float ls = l_part[qi];
    ls += __shfl_xor(ls, 16, 64);
    ls += __shfl_xor(ls, 32, 64);
    l_run[qi] = ls;
  }

  // ---- 2-way key-half merge (kh=1 publishes, kh=0 combines + writes) ----
  float* MO = (float*)smem;            // [4 qc][32 q][64 dk]
  float* ML = (float*)(smem + 32768);  // [128 q][2] {m, l}
  if (kh == 1) {
#pragma unroll
    for (int qi = 0; qi < 2; ++qi) {
#pragma unroll
      for (int j = 0; j < 4; ++j) {
        int row = qc * 32 + qi * 16 + lg * 4 + j;
#pragma unroll
        for (int dt = 0; dt < 4; ++dt)
          MO[(size_t)row * 64 + dt * 16 + rq] = o_acc[qi][dt][j];
      }
      if (lg == 0) {
        int row = qc * 32 + qi * 16 + rq;
        ML[row * 2 + 0] = m_run[qi];
        ML[row * 2 + 1] = l_run[qi];
      }
    }
  }
  __syncthreads();
  if (kh == 0) {
#pragma unroll
    for (int qi = 0; qi < 2; ++qi) {
      float m0c[4], l0c[4];
#pragma unroll
      for (int j = 0; j < 4; ++j) {
        m0c[j] = __shfl(m_run[qi], lg * 4 + j, 64);
        l0c[j] = __shfl(l_run[qi], lg * 4 + j, 64);
      }
#pragma unroll
      for (int j = 0; j < 4; ++j) {
        int row = qc * 32 + qi * 16 + lg * 4 + j;
        int r = q0 + qi * 16 + lg * 4 + j;
        float m1 = ML[row * 2 + 0], l1 = ML[row * 2 + 1];
        float mx = fmaxf(m0c[j], m1);
        float a0 = exp2_fast(m0c[j] - mx), a1 = exp2_fast(m1 - mx);
        float inv = 1.0f / (l0c[j] * a0 + l1 * a1);
#pragma unroll
        for (int dt = 0; dt < 4; ++dt) {
          float o = (o_acc[qi][dt][j] * a0 + MO[(size_t)row * 64 + dt * 16 + rq] * a1) * inv;
          Op[((size_t)b * Sc + r) * Dc + h * DKc + dt * 16 + rq] = f2bf(o);
        }
      }
    }
  }
}

// ---------------- launcher --------------------------------------------------
extern "C" void kernel_launch(void* const* d_in, const int* in_sizes, int n_in,
                              void* d_out, int out_size, void* d_ws, size_t ws_size,
                              hipStream_t stream) {
  const float* q_in = (const float*)d_in[0];
  const float* k_in = (const float*)d_in[1];
  const float* v_in = (const float*)d_in[2];
  const float* Wq = (const float*)d_in[3];
  const float* Wk = (const float*)d_in[4];
  const float* Wv = (const float*)d_in[5];
  const float* Wo = (const float*)d_in[6];

  unsigned short* wq_b = (unsigned short*)d_ws;
  unsigned short* wk_b = wq_b + Dc * Dc;
  unsigned short* wv_b = wk_b + Dc * Dc;
  unsigned short* wo_b = wv_b + Dc * Dc;
  unsigned short* qb = wo_b + Dc * Dc;
  unsigned short* kb = qb + (size_t)Mc * Dc;
  unsigned short* vb = kb + (size_t)Mc * Dc;
  unsigned short* ab = vb + (size_t)Mc * Dc;
  unsigned short* vt = ab + (size_t)Mc * Dc;  // V^T (key-permuted) per b

  dim3 cg(Dc * Dc / 4 / 256, 4);
  cast_w<<<cg, 256, 0, stream>>>(Wq, Wk, Wv, Wo, wq_b);

  dim3 gg(Dc / 64, Mc / 128);  // (8, 64) = 512 blocks
  gemm_bt<1, 0><<<gg, 256, 0, stream>>>(q_in, wq_b, qb, Mc, Dc, Dc);
  gemm_bt<1, 0><<<gg, 256, 0, stream>>>(k_in, wk_b, kb, Mc, Dc, Dc);
  gemm_bt<1, 0><<<gg, 256, 0, stream>>>(v_in, wv_b, vb, Mc, Dc, Dc);

  dim3 tg(Sc / 64, Dc / 64, Bc);
  transpose_v<<<tg, 256, 0, stream>>>(vb, vt);

  dim3 ga(Sc / 128, Bc * Hc);  // (32, 16) = 512 blocks, 512 thr
  attn_fwd<<<ga, 512, 0, stream>>>(qb, kb, vt, ab);

  gemm_bt<0, 1><<<gg, 256, 0, stream>>>(ab, wo_b, (float*)d_out, Mc, Dc, Dc);
}

// Round 15
// 181.118 us; speedup vs baseline: 1.2305x; 1.0290x over previous
//
#include <hip/hip_runtime.h>
#include <hip/hip_bf16.h>

typedef short short8 __attribute__((ext_vector_type(8)));
typedef short short4v __attribute__((ext_vector_type(4)));
typedef float floatx4 __attribute__((ext_vector_type(4)));
typedef unsigned int uint4v __attribute__((ext_vector_type(4)));

constexpr int Bc = 2, Sc = 4096, Dc = 512, Hc = 8, DKc = 64;
constexpr int Mc = Bc * Sc;  // 8192

static __device__ __forceinline__ unsigned short f2bf(float f) {
  unsigned int u = __builtin_bit_cast(unsigned int, f);
  unsigned int rb = ((u >> 16) & 1u) + 0x7fffu;
  return (unsigned short)((u + rb) >> 16);
}
// hardware packed f32x2 -> bf16x2 (RNE), 1 instruction
static __device__ __forceinline__ unsigned int cvt_pk_bf16(float lo, float hi) {
  unsigned int r;
  asm("v_cvt_pk_bf16_f32 %0, %1, %2" : "=v"(r) : "v"(lo), "v"(hi));
  return r;
}
// 2^x, 1 instruction
static __device__ __forceinline__ float exp2_fast(float x) {
  float r;
  asm("v_exp_f32 %0, %1" : "=v"(r) : "v"(x));
  return r;
}
// NOTE (R9-R11 lesson): v_permlane16/32_swap_b32 is BANNED this session.
// Cross-lane ops use only __shfl_xor (verified PASS R4-R8, R12, R13).

// ---------------- weight cast ------------------------------------------------
__global__ __launch_bounds__(256) void cast_w(
    const float* __restrict__ a, const float* __restrict__ b,
    const float* __restrict__ c, const float* __restrict__ d,
    unsigned short* __restrict__ out) {
  const float* srcs[4] = {a, b, c, d};
  const int m = blockIdx.y;
  const int i = (blockIdx.x * 256 + threadIdx.x) * 4;
  float4 v = *(const float4*)(srcs[m] + i);
  unsigned short t4[4] = {f2bf(v.x), f2bf(v.y), f2bf(v.z), f2bf(v.w)};
  *(short4v*)(out + (size_t)m * (Dc * Dc) + i) = *(short4v*)t4;
}

// ---------------- GEMM: Y[M,N] = X[M,K] @ W[N,K]^T ---------------------------
template <int IN_F32, int OUT_F32>
__global__ __launch_bounds__(256) void gemm_bt(
    const void* __restrict__ Xv, const unsigned short* __restrict__ Wb,
    void* __restrict__ Yv, int Mdim, int N, int K) {
  constexpr int BM = 128, BN = 64, BK = 32, LDP = 40;
  __shared__ unsigned short As[BM * LDP];
  __shared__ unsigned short Bs[BN * LDP];
  const int tid = threadIdx.x;
  const int lane = tid & 63, wid = tid >> 6;
  const int wm = wid >> 1, wn = wid & 1;
  const int bm = blockIdx.y * BM, bn = blockIdx.x * BN;
  const int rq = lane & 15, kk8 = (lane >> 4) * 8;
  const int sr = tid >> 1, sc = (tid & 1) * 16;
  const int brow = tid >> 2, bc8 = (tid & 3) * 8;

  floatx4 acc[4][2] = {};

  for (int k0 = 0; k0 < K; k0 += BK) {
    if (IN_F32) {
      const float* src = (const float*)Xv + (size_t)(bm + sr) * K + k0 + sc;
      unsigned int t2[8];
#pragma unroll
      for (int i = 0; i < 4; ++i) {
        float4 v = *(const float4*)(src + i * 4);
        t2[i * 2 + 0] = cvt_pk_bf16(v.x, v.y);
        t2[i * 2 + 1] = cvt_pk_bf16(v.z, v.w);
      }
      uint4v u0 = {t2[0], t2[1], t2[2], t2[3]};
      uint4v u1 = {t2[4], t2[5], t2[6], t2[7]};
      *(uint4v*)&As[sr * LDP + sc] = u0;
      *(uint4v*)&As[sr * LDP + sc + 8] = u1;
    } else {
      const unsigned short* src =
          (const unsigned short*)Xv + (size_t)(bm + sr) * K + k0 + sc;
      *(short8*)&As[sr * LDP + sc] = *(const short8*)src;
      *(short8*)&As[sr * LDP + sc + 8] = *(const short8*)(src + 8);
    }
    *(short8*)&Bs[brow * LDP + bc8] =
        *(const short8*)(Wb + (size_t)(bn + brow) * K + k0 + bc8);
    __syncthreads();

    short8 af[4], bfr[2];
#pragma unroll
    for (int mi = 0; mi < 4; ++mi)
      af[mi] = *(const short8*)&As[(wm * 64 + mi * 16 + rq) * LDP + kk8];
#pragma unroll
    for (int ni = 0; ni < 2; ++ni)
      bfr[ni] = *(const short8*)&Bs[(wn * 32 + ni * 16 + rq) * LDP + kk8];
#pragma unroll
    for (int mi = 0; mi < 4; ++mi)
#pragma unroll
      for (int ni = 0; ni < 2; ++ni)
        acc[mi][ni] = __builtin_amdgcn_mfma_f32_16x16x32_bf16(
            af[mi], bfr[ni], acc[mi][ni], 0, 0, 0);
    __syncthreads();
  }

#pragma unroll
  for (int mi = 0; mi < 4; ++mi)
#pragma unroll
    for (int ni = 0; ni < 2; ++ni)
#pragma unroll
      for (int j = 0; j < 4; ++j) {
        int r = bm + wm * 64 + mi * 16 + (lane >> 4) * 4 + j;
        int c = bn + wn * 32 + ni * 16 + rq;
        float v = acc[mi][ni][j];
        if (OUT_F32)
          ((float*)Yv)[(size_t)r * N + c] = v;
        else
          ((unsigned short*)Yv)[(size_t)r * N + c] = f2bf(v);
      }
}

// ---------------- V transpose + key-permute ---------------------------------
// vt[b][dk][s'] = vb[b][key][dk], where s' = sigma(key) permutes each aligned
// 32-key group so attn's PV A-fragment is lane-local (P never leaves the
// lane's registers). sigma(key bits [k4 k3 k2 k1 k0]) = [k3 k2 k4 k1 k0]:
//   pos = ((key>>2)&3)*8 + ((key>>4)&1)*4 + (key&3).
__global__ __launch_bounds__(256) void transpose_v(
    const unsigned short* __restrict__ vb, unsigned short* __restrict__ vt) {
  constexpr int LDT = 65;
  __shared__ unsigned short T[64 * LDT];
  const int tid = threadIdx.x;
  const int s0 = blockIdx.x * 64, c0 = blockIdx.y * 64, b = blockIdx.z;
  const int r = tid >> 2, cs = (tid & 3) * 16;
  const unsigned short* src = vb + ((size_t)b * Sc + s0 + r) * Dc + c0 + cs;
  *(short8*)&T[r * LDT + cs] = *(const short8*)src;
  *(short8*)&T[r * LDT + cs + 8] = *(const short8*)(src + 8);
  __syncthreads();
  unsigned short tmp[16];
#pragma unroll
  for (int j = 0; j < 16; ++j) tmp[j] = T[(cs + j) * LDT + r];
  const int k4 = (cs >> 4) & 1;
  const int base32 = s0 + (cs & 32);
  unsigned short* dstrow = vt + ((size_t)b * Dc + c0 + r) * Sc;
#pragma unroll
  for (int g = 0; g < 4; ++g) {  // g = j>>2 = k3k2
    short4v v4 = {(short)tmp[4 * g + 0], (short)tmp[4 * g + 1],
                  (short)tmp[4 * g + 2], (short)tmp[4 * g + 3]};
    *(short4v*)(dstrow + base32 + g * 8 + k4 * 4) = v4;
  }
}

// ---------------- flash attention --------------------------------------------
// Block = 128 q-rows, 8 waves = 4 q-chunks (qc, 32q) x 2 key-halves (kh, 32k).
// Swapped QK^T; zero-cross-lane softmax common path (defer-max THR=8 +
// deferred l, R12); in-register P via sigma key-permute (R13).
// R14: DOUBLE-BUFFERED K/V tiles + ONE barrier per iter + early global
// load issue (T14): next tile's global->reg loads are issued right after the
// barrier and stay in flight under QK^T+softmax+PV; ds_write lands in the
// alternate buffer at the end of the body. Removes 1 barrier + the serial
// HBM round-trip (~500cy) per iteration.
// launch_bounds (512,4): VGPR cap 128 (R5: tighter cap => scratch spill).
__global__ __launch_bounds__(512, 4) void attn_fwd(
    const unsigned short* __restrict__ Qp, const unsigned short* __restrict__ Kp,
    const unsigned short* __restrict__ Vtp, unsigned short* __restrict__ Op) {
  // LDS bytes: Ks [0,16384) 2buf x [64][64] swz; Vs [16384,32768) 2buf V^T.
  // Merge overlay: MO f32 [128 q][64 dk] @0 (32KB), ML f32 [128][2] @32768.
  __shared__ unsigned char smem[33792];
  unsigned short* KsB = (unsigned short*)smem;           // [2][4096]
  unsigned short* VsB = (unsigned short*)(smem + 16384); // [2][4096]

  const int tid = threadIdx.x, lane = tid & 63, wid = tid >> 6;
  const int qc = wid >> 1, kh = wid & 1;
  const int b = blockIdx.y >> 3, h = blockIdx.y & 7;
  const int q0 = blockIdx.x * 128 + qc * 32;
  const int rq = lane & 15, lg = lane >> 4, kk8 = lg * 8;

  const unsigned short* Qb = Qp + ((size_t)b * Sc) * Dc + h * DKc;
  const unsigned short* Kb = Kp + ((size_t)b * Sc) * Dc + h * DKc;
  const unsigned short* Vh = Vtp + ((size_t)b * Dc + h * DKc) * Sc;

  // Q as B-fragment: col = lane&15 = q-local, k = (lane>>4)*8+j
  short8 qa[2][2];
#pragma unroll
  for (int qi = 0; qi < 2; ++qi)
#pragma unroll
    for (int c = 0; c < 2; ++c)
      qa[qi][c] = *(const short8*)(Qb + (size_t)(q0 + qi * 16 + rq) * Dc + c * 32 + kk8);

  floatx4 o_acc[2][4] = {};
  float l_part[2] = {0.f, 0.f};       // per-lane PARTIAL sum (own 8 keys)
  float m_run[2] = {-1e30f, -1e30f};  // per-lane (q = lane&15), log2 domain

  const float C2 = 0.18033688f;   // (1/sqrt(64)) * log2(e)
  const float THR = 8.0f;         // defer-max bound: P <= 2^8

  // staging: 512 threads stage K[64][64] + V^T[64][64], 16B each, XOR swizzle
  const int sr = tid >> 3, sc8 = (tid & 7) * 8;
  const int st = (sr * 64 + sc8) ^ ((sr & 7) << 3);
  const int sx = (rq & 7) << 3;

  // prologue: tile 0 -> regs -> buf0
  short8 kr = *(const short8*)(Kb + (size_t)sr * Dc + sc8);
  short8 vr = *(const short8*)(Vh + (size_t)sr * Sc + sc8);
  *(short8*)&KsB[st] = kr;
  *(short8*)&VsB[st] = vr;

  for (int it = 0; it < 64; ++it) {
    const int cur = it & 1;
    __syncthreads();  // buf[cur] writes visible; buf[cur^1] reads (iter it-1) done

    if (it < 63) {  // issue next tile's global loads; land during compute
      const int kn = (it + 1) * 64;
      kr = *(const short8*)(Kb + (size_t)(kn + sr) * Dc + sc8);
      vr = *(const short8*)(Vh + (size_t)sr * Sc + kn + sc8);
    }

    const unsigned short* Ks = KsB + cur * 4096;
    const unsigned short* Vs = VsB + cur * 4096;

    // K A-frags for this wave's key-half (shared across both q-subtiles)
    short8 ka[2][2];
#pragma unroll
    for (int ks = 0; ks < 2; ++ks)
#pragma unroll
      for (int c = 0; c < 2; ++c) {
        const int row = kh * 32 + ks * 16 + rq;
        ka[ks][c] = *(const short8*)&Ks[(row * 64 + c * 32 + kk8) ^ sx];
      }

    short8 pb_[2];  // per-qi PV A-frags, built fully in-register
#pragma unroll
    for (int qi = 0; qi < 2; ++qi) {
      // swapped QK^T: s[ks][j] = S^T[key = kh*32+ks*16+lg*4+j][q = rq]
      floatx4 s[2] = {};
#pragma unroll
      for (int ks = 0; ks < 2; ++ks) {
        s[ks] = __builtin_amdgcn_mfma_f32_16x16x32_bf16(ka[ks][0], qa[qi][0], s[ks], 0, 0, 0);
        s[ks] = __builtin_amdgcn_mfma_f32_16x16x32_bf16(ka[ks][1], qa[qi][1], s[ks], 0, 0, 0);
      }
      // per-lane partial max over own 8 keys (no cross-lane on common path)
      float tp = fmaxf(fmaxf(fmaxf(s[0][0], s[0][1]), fmaxf(s[0][2], s[0][3])),
                       fmaxf(fmaxf(s[1][0], s[1][1]), fmaxf(s[1][2], s[1][3]))) * C2;

      if (__any(tp > m_run[qi] + THR)) {  // rare: bound would be exceeded
        float tm = tp;
        tm = fmaxf(tm, __shfl_xor(tm, 16, 64));
        tm = fmaxf(tm, __shfl_xor(tm, 32, 64));
        if (__any(tm > m_run[qi])) {
          float mn = fmaxf(m_run[qi], tm);
          float scf = exp2_fast(m_run[qi] - mn);
          m_run[qi] = mn;
          l_part[qi] *= scf;
          float sc_c[4];
#pragma unroll
          for (int j = 0; j < 4; ++j) sc_c[j] = __shfl(scf, lg * 4 + j, 64);
#pragma unroll
          for (int j = 0; j < 4; ++j)
#pragma unroll
            for (int dt = 0; dt < 4; ++dt) o_acc[qi][dt][j] *= sc_c[j];
        }
      }

      // P = 2^(s*C2 - m), packed in A-frag slot order (sigma-matched)
      const float lm = m_run[qi];
      unsigned int pw0, pw1, pw2, pw3;
      {
        float p0 = exp2_fast(fmaf(s[0][0], C2, -lm));
        float p1 = exp2_fast(fmaf(s[0][1], C2, -lm));
        float p2 = exp2_fast(fmaf(s[0][2], C2, -lm));
        float p3 = exp2_fast(fmaf(s[0][3], C2, -lm));
        l_part[qi] += (p0 + p1) + (p2 + p3);
        pw0 = cvt_pk_bf16(p0, p1);
        pw1 = cvt_pk_bf16(p2, p3);
      }
      {
        float p0 = exp2_fast(fmaf(s[1][0], C2, -lm));
        float p1 = exp2_fast(fmaf(s[1][1], C2, -lm));
        float p2 = exp2_fast(fmaf(s[1][2], C2, -lm));
        float p3 = exp2_fast(fmaf(s[1][3], C2, -lm));
        l_part[qi] += (p0 + p1) + (p2 + p3);
        pw2 = cvt_pk_bf16(p0, p1);
        pw3 = cvt_pk_bf16(p2, p3);
      }
      uint4v pw = {pw0, pw1, pw2, pw3};
      pb_[qi] = __builtin_bit_cast(short8, pw);
    }

    // PV: A = pb_ (in-register), B = key-permuted V^T rows, K=32 = key-half
#pragma unroll
    for (int dt = 0; dt < 4; ++dt) {
      const int vrow = dt * 16 + rq;
      short8 v = *(const short8*)&Vs[(vrow * 64 + kh * 32 + kk8) ^ sx];
      o_acc[0][dt] = __builtin_amdgcn_mfma_f32_16x16x32_bf16(pb_[0], v, o_acc[0][dt], 0, 0, 0);
      o_acc[1][dt] = __builtin_amdgcn_mfma_f32_16x16x32_bf16(pb_[1], v, o_acc[1][dt], 0, 0, 0);
    }

    if (it < 63) {  // write next tile into the alternate buffer
      *(short8*)&KsB[(cur ^ 1) * 4096 + st] = kr;
      *(short8*)&VsB[(cur ^ 1) * 4096 + st] = vr;
    }
  }

  // finalize l: one cross-lane reduce of the partial sums (2 shfls per qi)
  float l_run[2];
#pragma unroll
  for (int qi = 0; qi < 2; ++qi) {
    float ls = l_part[qi];
    ls += __shfl_xor(ls, 16, 64);
    ls += __shfl_xor(ls, 32, 64);
    l_run[qi] = ls;
  }

  __syncthreads();  // all K-loop LDS traffic done before merge overlay
  // ---- 2-way key-half merge (kh=1 publishes, kh=0 combines + writes) ----
  float* MO = (float*)smem;            // [4 qc][32 q][64 dk]
  float* ML = (float*)(smem + 32768);  // [128 q][2] {m, l}
  if (kh == 1) {
#pragma unroll
    for (int qi = 0; qi < 2; ++qi) {
#pragma unroll
      for (int j = 0; j < 4; ++j) {
        int row = qc * 32 + qi * 16 + lg * 4 + j;
#pragma unroll
        for (int dt = 0; dt < 4; ++dt)
          MO[(size_t)row * 64 + dt * 16 + rq] = o_acc[qi][dt][j];
      }
      if (lg == 0) {
        int row = qc * 32 + qi * 16 + rq;
        ML[row * 2 + 0] = m_run[qi];
        ML[row * 2 + 1] = l_run[qi];
      }
    }
  }
  __syncthreads();
  if (kh == 0) {
#pragma unroll
    for (int qi = 0; qi < 2; ++qi) {
      float m0c[4], l0c[4];
#pragma unroll
      for (int j = 0; j < 4; ++j) {
        m0c[j] = __shfl(m_run[qi], lg * 4 + j, 64);
        l0c[j] = __shfl(l_run[qi], lg * 4 + j, 64);
      }
#pragma unroll
      for (int j = 0; j < 4; ++j) {
        int row = qc * 32 + qi * 16 + lg * 4 + j;
        int r = q0 + qi * 16 + lg * 4 + j;
        float m1 = ML[row * 2 + 0], l1 = ML[row * 2 + 1];
        float mx = fmaxf(m0c[j], m1);
        float a0 = exp2_fast(m0c[j] - mx), a1 = exp2_fast(m1 - mx);
        float inv = 1.0f / (l0c[j] * a0 + l1 * a1);
#pragma unroll
        for (int dt = 0; dt < 4; ++dt) {
          float o = (o_acc[qi][dt][j] * a0 + MO[(size_t)row * 64 + dt * 16 + rq] * a1) * inv;
          Op[((size_t)b * Sc + r) * Dc + h * DKc + dt * 16 + rq] = f2bf(o);
        }
      }
    }
  }
}

// ---------------- launcher --------------------------------------------------
extern "C" void kernel_launch(void* const* d_in, const int* in_sizes, int n_in,
                              void* d_out, int out_size, void* d_ws, size_t ws_size,
                              hipStream_t stream) {
  const float* q_in = (const float*)d_in[0];
  const float* k_in = (const float*)d_in[1];
  const float* v_in = (const float*)d_in[2];
  const float* Wq = (const float*)d_in[3];
  const float* Wk = (const float*)d_in[4];
  const float* Wv = (const float*)d_in[5];
  const float* Wo = (const float*)d_in[6];

  unsigned short* wq_b = (unsigned short*)d_ws;
  unsigned short* wk_b = wq_b + Dc * Dc;
  unsigned short* wv_b = wk_b + Dc * Dc;
  unsigned short* wo_b = wv_b + Dc * Dc;
  unsigned short* qb = wo_b + Dc * Dc;
  unsigned short* kb = qb + (size_t)Mc * Dc;
  unsigned short* vb = kb + (size_t)Mc * Dc;
  unsigned short* ab = vb + (size_t)Mc * Dc;
  unsigned short* vt = ab + (size_t)Mc * Dc;  // V^T (key-permuted) per b

  dim3 cg(Dc * Dc / 4 / 256, 4);
  cast_w<<<cg, 256, 0, stream>>>(Wq, Wk, Wv, Wo, wq_b);

  dim3 gg(Dc / 64, Mc / 128);  // (8, 64) = 512 blocks
  gemm_bt<1, 0><<<gg, 256, 0, stream>>>(q_in, wq_b, qb, Mc, Dc, Dc);
  gemm_bt<1, 0><<<gg, 256, 0, stream>>>(k_in, wk_b, kb, Mc, Dc, Dc);
  gemm_bt<1, 0><<<gg, 256, 0, stream>>>(v_in, wv_b, vb, Mc, Dc, Dc);

  dim3 tg(Sc / 64, Dc / 64, Bc);
  transpose_v<<<tg, 256, 0, stream>>>(vb, vt);

  dim3 ga(Sc / 128, Bc * Hc);  // (32, 16) = 512 blocks, 512 thr
  attn_fwd<<<ga, 512, 0, stream>>>(qb, kb, vt, ab);

  gemm_bt<0, 1><<<gg, 256, 0, stream>>>(ab, wo_b, (float*)d_out, Mc, Dc, Dc);
}

// Round 16
// 174.513 us; speedup vs baseline: 1.2770x; 1.0378x over previous
//
#include <hip/hip_runtime.h>
#include <hip/hip_bf16.h>

typedef short short8 __attribute__((ext_vector_type(8)));
typedef short short4v __attribute__((ext_vector_type(4)));
typedef float floatx4 __attribute__((ext_vector_type(4)));
typedef unsigned int uint4v __attribute__((ext_vector_type(4)));

constexpr int Bc = 2, Sc = 4096, Dc = 512, Hc = 8, DKc = 64;
constexpr int Mc = Bc * Sc;  // 8192

static __device__ __forceinline__ unsigned short f2bf(float f) {
  unsigned int u = __builtin_bit_cast(unsigned int, f);
  unsigned int rb = ((u >> 16) & 1u) + 0x7fffu;
  return (unsigned short)((u + rb) >> 16);
}
// hardware packed f32x2 -> bf16x2 (RNE), 1 instruction
static __device__ __forceinline__ unsigned int cvt_pk_bf16(float lo, float hi) {
  unsigned int r;
  asm("v_cvt_pk_bf16_f32 %0, %1, %2" : "=v"(r) : "v"(lo), "v"(hi));
  return r;
}
// 2^x, 1 instruction
static __device__ __forceinline__ float exp2_fast(float x) {
  float r;
  asm("v_exp_f32 %0, %1" : "=v"(r) : "v"(x));
  return r;
}
// NOTE (R9-R11 lesson): v_permlane16/32_swap_b32 is BANNED this session.
// Cross-lane ops use only __shfl_xor (verified PASS R4-R8, R12, R13, R15).

// ---------------- GEMM body: Y[M,N] = X[M,K] @ W[N,K]^T ----------------------
// Double-buffered (R14/R15-proven pattern): one barrier per K-iter; next
// tile's global loads issued right after the barrier fly under the MFMAs.
// W_F32: weights are f32, converted to bf16 via cvt_pk during staging
// (replaces the separate cast_w kernel; weight re-reads are L2-resident).
template <int IN_F32, int OUT_F32, int W_F32>
static __device__ __forceinline__ void gemm_body(
    const void* __restrict__ Xv, const void* __restrict__ Wp,
    void* __restrict__ Yv, const int N, const int K) {
  constexpr int BM = 128, BN = 64, BK = 32, LDP = 40;
  __shared__ unsigned short As[2][BM * LDP];
  __shared__ unsigned short Bs[2][BN * LDP];
  const int tid = threadIdx.x;
  const int lane = tid & 63, wid = tid >> 6;
  const int wm = wid >> 1, wn = wid & 1;
  const int bm = blockIdx.y * BM, bn = blockIdx.x * BN;
  const int rq = lane & 15, kk8 = (lane >> 4) * 8;
  const int sr = tid >> 1, sc = (tid & 1) * 16;   // A: 16 elems/thread
  const int brow = tid >> 2, bc8 = (tid & 3) * 8; // B: 8 elems/thread

  floatx4 acc[4][2] = {};

  // in-flight staging registers
  float a32[16];
  short8 a16[2];
  float b32[8];
  short8 b16;

  auto load_tile = [&](int k0) {
    if (IN_F32) {
      const float* src = (const float*)Xv + (size_t)(bm + sr) * K + k0 + sc;
#pragma unroll
      for (int i = 0; i < 4; ++i) {
        float4 v = *(const float4*)(src + i * 4);
        a32[4 * i + 0] = v.x; a32[4 * i + 1] = v.y;
        a32[4 * i + 2] = v.z; a32[4 * i + 3] = v.w;
      }
    } else {
      const unsigned short* src =
          (const unsigned short*)Xv + (size_t)(bm + sr) * K + k0 + sc;
      a16[0] = *(const short8*)src;
      a16[1] = *(const short8*)(src + 8);
    }
    if (W_F32) {
      const float* wsrc = (const float*)Wp + (size_t)(bn + brow) * K + k0 + bc8;
#pragma unroll
      for (int i = 0; i < 2; ++i) {
        float4 v = *(const float4*)(wsrc + i * 4);
        b32[4 * i + 0] = v.x; b32[4 * i + 1] = v.y;
        b32[4 * i + 2] = v.z; b32[4 * i + 3] = v.w;
      }
    } else {
      b16 = *(const short8*)((const unsigned short*)Wp +
                             (size_t)(bn + brow) * K + k0 + bc8);
    }
  };
  auto store_tile = [&](int bf) {
    if (IN_F32) {
      unsigned int t2[8];
#pragma unroll
      for (int i = 0; i < 8; ++i) t2[i] = cvt_pk_bf16(a32[2 * i], a32[2 * i + 1]);
      uint4v u0 = {t2[0], t2[1], t2[2], t2[3]};
      uint4v u1 = {t2[4], t2[5], t2[6], t2[7]};
      *(uint4v*)&As[bf][sr * LDP + sc] = u0;
      *(uint4v*)&As[bf][sr * LDP + sc + 8] = u1;
    } else {
      *(short8*)&As[bf][sr * LDP + sc] = a16[0];
      *(short8*)&As[bf][sr * LDP + sc + 8] = a16[1];
    }
    if (W_F32) {
      unsigned int t2[4];
#pragma unroll
      for (int i = 0; i < 4; ++i) t2[i] = cvt_pk_bf16(b32[2 * i], b32[2 * i + 1]);
      uint4v u = {t2[0], t2[1], t2[2], t2[3]};
      *(uint4v*)&Bs[bf][brow * LDP + bc8] = u;
    } else {
      *(short8*)&Bs[bf][brow * LDP + bc8] = b16;
    }
  };

  // prologue: tile 0 -> regs -> buf0
  load_tile(0);
  store_tile(0);

  const int NK = K / BK;  // 16
  for (int it = 0; it < NK; ++it) {
    const int cur = it & 1;
    __syncthreads();  // buf[cur] writes visible; buf[cur^1] reads done

    if (it < NK - 1) load_tile((it + 1) * BK);  // in flight under MFMAs

    short8 af[4], bfr[2];
#pragma unroll
    for (int mi = 0; mi < 4; ++mi)
      af[mi] = *(const short8*)&As[cur][(wm * 64 + mi * 16 + rq) * LDP + kk8];
#pragma unroll
    for (int ni = 0; ni < 2; ++ni)
      bfr[ni] = *(const short8*)&Bs[cur][(wn * 32 + ni * 16 + rq) * LDP + kk8];
#pragma unroll
    for (int mi = 0; mi < 4; ++mi)
#pragma unroll
      for (int ni = 0; ni < 2; ++ni)
        acc[mi][ni] = __builtin_amdgcn_mfma_f32_16x16x32_bf16(
            af[mi], bfr[ni], acc[mi][ni], 0, 0, 0);

    if (it < NK - 1) store_tile(cur ^ 1);
  }

#pragma unroll
  for (int mi = 0; mi < 4; ++mi)
#pragma unroll
    for (int ni = 0; ni < 2; ++ni)
#pragma unroll
      for (int j = 0; j < 4; ++j) {
        int r = bm + wm * 64 + mi * 16 + (lane >> 4) * 4 + j;
        int c = bn + wn * 32 + ni * 16 + rq;
        float v = acc[mi][ni][j];
        if (OUT_F32)
          ((float*)Yv)[(size_t)r * N + c] = v;
        else
          ((unsigned short*)Yv)[(size_t)r * N + c] = f2bf(v);
      }
}

// batched Q/K/V projection: blockIdx.z selects (input, weight, output).
// f32 input, f32 weight (cast fused into staging), bf16 output.
__global__ __launch_bounds__(256) void gemm_qkv(
    const float* __restrict__ xq, const float* __restrict__ xk,
    const float* __restrict__ xv, const float* __restrict__ wq,
    const float* __restrict__ wk, const float* __restrict__ wv,
    unsigned short* __restrict__ yq, unsigned short* __restrict__ yk,
    unsigned short* __restrict__ yv) {
  const int z = blockIdx.z;
  const float* X = (z == 0) ? xq : (z == 1) ? xk : xv;
  const float* W = (z == 0) ? wq : (z == 1) ? wk : wv;
  unsigned short* Y = (z == 0) ? yq : (z == 1) ? yk : yv;
  gemm_body<1, 0, 1>(X, W, Y, Dc, Dc);
}

// output projection: bf16 input, f32 weight, f32 output.
__global__ __launch_bounds__(256) void gemm_out(
    const unsigned short* __restrict__ x, const float* __restrict__ w,
    float* __restrict__ y) {
  gemm_body<0, 1, 1>(x, w, y, Dc, Dc);
}

// ---------------- V transpose + key-permute ---------------------------------
// vt[b][dk][s'] = vb[b][key][dk], where s' = sigma(key) permutes each aligned
// 32-key group so attn's PV A-fragment is lane-local (P never leaves the
// lane's registers). sigma(key bits [k4 k3 k2 k1 k0]) = [k3 k2 k4 k1 k0]:
//   pos = ((key>>2)&3)*8 + ((key>>4)&1)*4 + (key&3).
__global__ __launch_bounds__(256) void transpose_v(
    const unsigned short* __restrict__ vb, unsigned short* __restrict__ vt) {
  constexpr int LDT = 65;
  __shared__ unsigned short T[64 * LDT];
  const int tid = threadIdx.x;
  const int s0 = blockIdx.x * 64, c0 = blockIdx.y * 64, b = blockIdx.z;
  const int r = tid >> 2, cs = (tid & 3) * 16;
  const unsigned short* src = vb + ((size_t)b * Sc + s0 + r) * Dc + c0 + cs;
  *(short8*)&T[r * LDT + cs] = *(const short8*)src;
  *(short8*)&T[r * LDT + cs + 8] = *(const short8*)(src + 8);
  __syncthreads();
  unsigned short tmp[16];
#pragma unroll
  for (int j = 0; j < 16; ++j) tmp[j] = T[(cs + j) * LDT + r];
  const int k4 = (cs >> 4) & 1;
  const int base32 = s0 + (cs & 32);
  unsigned short* dstrow = vt + ((size_t)b * Dc + c0 + r) * Sc;
#pragma unroll
  for (int g = 0; g < 4; ++g) {  // g = j>>2 = k3k2
    short4v v4 = {(short)tmp[4 * g + 0], (short)tmp[4 * g + 1],
                  (short)tmp[4 * g + 2], (short)tmp[4 * g + 3]};
    *(short4v*)(dstrow + base32 + g * 8 + k4 * 4) = v4;
  }
}

// ---------------- flash attention (R15, UNCHANGED — canary) ------------------
// Block = 128 q-rows, 8 waves = 4 q-chunks (qc, 32q) x 2 key-halves (kh, 32k).
// Swapped QK^T; zero-cross-lane softmax common path (defer-max THR=8 +
// deferred l); in-register P via sigma key-permute; double-buffered K/V with
// one barrier per iter + early global load issue.
// launch_bounds (512,4): VGPR cap 128 (R5: tighter cap => scratch spill).
__global__ __launch_bounds__(512, 4) void attn_fwd(
    const unsigned short* __restrict__ Qp, const unsigned short* __restrict__ Kp,
    const unsigned short* __restrict__ Vtp, unsigned short* __restrict__ Op) {
  // LDS bytes: Ks [0,16384) 2buf x [64][64] swz; Vs [16384,32768) 2buf V^T.
  // Merge overlay: MO f32 [128 q][64 dk] @0 (32KB), ML f32 [128][2] @32768.
  __shared__ unsigned char smem[33792];
  unsigned short* KsB = (unsigned short*)smem;           // [2][4096]
  unsigned short* VsB = (unsigned short*)(smem + 16384); // [2][4096]

  const int tid = threadIdx.x, lane = tid & 63, wid = tid >> 6;
  const int qc = wid >> 1, kh = wid & 1;
  const int b = blockIdx.y >> 3, h = blockIdx.y & 7;
  const int q0 = blockIdx.x * 128 + qc * 32;
  const int rq = lane & 15, lg = lane >> 4, kk8 = lg * 8;

  const unsigned short* Qb = Qp + ((size_t)b * Sc) * Dc + h * DKc;
  const unsigned short* Kb = Kp + ((size_t)b * Sc) * Dc + h * DKc;
  const unsigned short* Vh = Vtp + ((size_t)b * Dc + h * DKc) * Sc;

  // Q as B-fragment: col = lane&15 = q-local, k = (lane>>4)*8+j
  short8 qa[2][2];
#pragma unroll
  for (int qi = 0; qi < 2; ++qi)
#pragma unroll
    for (int c = 0; c < 2; ++c)
      qa[qi][c] = *(const short8*)(Qb + (size_t)(q0 + qi * 16 + rq) * Dc + c * 32 + kk8);

  floatx4 o_acc[2][4] = {};
  float l_part[2] = {0.f, 0.f};       // per-lane PARTIAL sum (own 8 keys)
  float m_run[2] = {-1e30f, -1e30f};  // per-lane (q = lane&15), log2 domain

  const float C2 = 0.18033688f;   // (1/sqrt(64)) * log2(e)
  const float THR = 8.0f;         // defer-max bound: P <= 2^8

  // staging: 512 threads stage K[64][64] + V^T[64][64], 16B each, XOR swizzle
  const int sr = tid >> 3, sc8 = (tid & 7) * 8;
  const int st = (sr * 64 + sc8) ^ ((sr & 7) << 3);
  const int sx = (rq & 7) << 3;

  // prologue: tile 0 -> regs -> buf0
  short8 kr = *(const short8*)(Kb + (size_t)sr * Dc + sc8);
  short8 vr = *(const short8*)(Vh + (size_t)sr * Sc + sc8);
  *(short8*)&KsB[st] = kr;
  *(short8*)&VsB[st] = vr;

  for (int it = 0; it < 64; ++it) {
    const int cur = it & 1;
    __syncthreads();  // buf[cur] writes visible; buf[cur^1] reads done

    if (it < 63) {  // issue next tile's global loads; land during compute
      const int kn = (it + 1) * 64;
      kr = *(const short8*)(Kb + (size_t)(kn + sr) * Dc + sc8);
      vr = *(const short8*)(Vh + (size_t)sr * Sc + kn + sc8);
    }

    const unsigned short* Ks = KsB + cur * 4096;
    const unsigned short* Vs = VsB + cur * 4096;

    // K A-frags for this wave's key-half (shared across both q-subtiles)
    short8 ka[2][2];
#pragma unroll
    for (int ks = 0; ks < 2; ++ks)
#pragma unroll
      for (int c = 0; c < 2; ++c) {
        const int row = kh * 32 + ks * 16 + rq;
        ka[ks][c] = *(const short8*)&Ks[(row * 64 + c * 32 + kk8) ^ sx];
      }

    short8 pb_[2];  // per-qi PV A-frags, built fully in-register
#pragma unroll
    for (int qi = 0; qi < 2; ++qi) {
      // swapped QK^T: s[ks][j] = S^T[key = kh*32+ks*16+lg*4+j][q = rq]
      floatx4 s[2] = {};
#pragma unroll
      for (int ks = 0; ks < 2; ++ks) {
        s[ks] = __builtin_amdgcn_mfma_f32_16x16x32_bf16(ka[ks][0], qa[qi][0], s[ks], 0, 0, 0);
        s[ks] = __builtin_amdgcn_mfma_f32_16x16x32_bf16(ka[ks][1], qa[qi][1], s[ks], 0, 0, 0);
      }
      // per-lane partial max over own 8 keys (no cross-lane on common path)
      float tp = fmaxf(fmaxf(fmaxf(s[0][0], s[0][1]), fmaxf(s[0][2], s[0][3])),
                       fmaxf(fmaxf(s[1][0], s[1][1]), fmaxf(s[1][2], s[1][3]))) * C2;

      if (__any(tp > m_run[qi] + THR)) {  // rare: bound would be exceeded
        float tm = tp;
        tm = fmaxf(tm, __shfl_xor(tm, 16, 64));
        tm = fmaxf(tm, __shfl_xor(tm, 32, 64));
        if (__any(tm > m_run[qi])) {
          float mn = fmaxf(m_run[qi], tm);
          float scf = exp2_fast(m_run[qi] - mn);
          m_run[qi] = mn;
          l_part[qi] *= scf;
          float sc_c[4];
#pragma unroll
          for (int j = 0; j < 4; ++j) sc_c[j] = __shfl(scf, lg * 4 + j, 64);
#pragma unroll
          for (int j = 0; j < 4; ++j)
#pragma unroll
            for (int dt = 0; dt < 4; ++dt) o_acc[qi][dt][j] *= sc_c[j];
        }
      }

      // P = 2^(s*C2 - m), packed in A-frag slot order (sigma-matched)
      const float lm = m_run[qi];
      unsigned int pw0, pw1, pw2, pw3;
      {
        float p0 = exp2_fast(fmaf(s[0][0], C2, -lm));
        float p1 = exp2_fast(fmaf(s[0][1], C2, -lm));
        float p2 = exp2_fast(fmaf(s[0][2], C2, -lm));
        float p3 = exp2_fast(fmaf(s[0][3], C2, -lm));
        l_part[qi] += (p0 + p1) + (p2 + p3);
        pw0 = cvt_pk_bf16(p0, p1);
        pw1 = cvt_pk_bf16(p2, p3);
      }
      {
        float p0 = exp2_fast(fmaf(s[1][0], C2, -lm));
        float p1 = exp2_fast(fmaf(s[1][1], C2, -lm));
        float p2 = exp2_fast(fmaf(s[1][2], C2, -lm));
        float p3 = exp2_fast(fmaf(s[1][3], C2, -lm));
        l_part[qi] += (p0 + p1) + (p2 + p3);
        pw2 = cvt_pk_bf16(p0, p1);
        pw3 = cvt_pk_bf16(p2, p3);
      }
      uint4v pw = {pw0, pw1, pw2, pw3};
      pb_[qi] = __builtin_bit_cast(short8, pw);
    }

    // PV: A = pb_ (in-register), B = key-permuted V^T rows, K=32 = key-half
#pragma unroll
    for (int dt = 0; dt < 4; ++dt) {
      const int vrow = dt * 16 + rq;
      short8 v = *(const short8*)&Vs[(vrow * 64 + kh * 32 + kk8) ^ sx];
      o_acc[0][dt] = __builtin_amdgcn_mfma_f32_16x16x32_bf16(pb_[0], v, o_acc[0][dt], 0, 0, 0);
      o_acc[1][dt] = __builtin_amdgcn_mfma_f32_16x16x32_bf16(pb_[1], v, o_acc[1][dt], 0, 0, 0);
    }

    if (it < 63) {  // write next tile into the alternate buffer
      *(short8*)&KsB[(cur ^ 1) * 4096 + st] = kr;
      *(short8*)&VsB[(cur ^ 1) * 4096 + st] = vr;
    }
  }

  // finalize l: one cross-lane reduce of the partial sums (2 shfls per qi)
  float l_run[2];
#pragma unroll
  for (int qi = 0; qi < 2; ++qi) {
    float ls = l_part[qi];
    ls += __shfl_xor(ls, 16, 64);
    ls += __shfl_xor(ls, 32, 64);
    l_run[qi] = ls;
  }

  __syncthreads();  // all K-loop LDS traffic done before merge overlay
  // ---- 2-way key-half merge (kh=1 publishes, kh=0 combines + writes) ----
  float* MO = (float*)smem;            // [4 qc][32 q][64 dk]
  float* ML = (float*)(smem + 32768);  // [128 q][2] {m, l}
  if (kh == 1) {
#pragma unroll
    for (int qi = 0; qi < 2; ++qi) {
#pragma unroll
      for (int j = 0; j < 4; ++j) {
        int row = qc * 32 + qi * 16 + lg * 4 + j;
#pragma unroll
        for (int dt = 0; dt < 4; ++dt)
          MO[(size_t)row * 64 + dt * 16 + rq] = o_acc[qi][dt][j];
      }
      if (lg == 0) {
        int row = qc * 32 + qi * 16 + rq;
        ML[row * 2 + 0] = m_run[qi];
        ML[row * 2 + 1] = l_run[qi];
      }
    }
  }
  __syncthreads();
  if (kh == 0) {
#pragma unroll
    for (int qi = 0; qi < 2; ++qi) {
      float m0c[4], l0c[4];
#pragma unroll
      for (int j = 0; j < 4; ++j) {
        m0c[j] = __shfl(m_run[qi], lg * 4 + j, 64);
        l0c[j] = __shfl(l_run[qi], lg * 4 + j, 64);
      }
#pragma unroll
      for (int j = 0; j < 4; ++j) {
        int row = qc * 32 + qi * 16 + lg * 4 + j;
        int r = q0 + qi * 16 + lg * 4 + j;
        float m1 = ML[row * 2 + 0], l1 = ML[row * 2 + 1];
        float mx = fmaxf(m0c[j], m1);
        float a0 = exp2_fast(m0c[j] - mx), a1 = exp2_fast(m1 - mx);
        float inv = 1.0f / (l0c[j] * a0 + l1 * a1);
#pragma unroll
        for (int dt = 0; dt < 4; ++dt) {
          float o = (o_acc[qi][dt][j] * a0 + MO[(size_t)row * 64 + dt * 16 + rq] * a1) * inv;
          Op[((size_t)b * Sc + r) * Dc + h * DKc + dt * 16 + rq] = f2bf(o);
        }
      }
    }
  }
}

// ---------------- launcher --------------------------------------------------
extern "C" void kernel_launch(void* const* d_in, const int* in_sizes, int n_in,
                              void* d_out, int out_size, void* d_ws, size_t ws_size,
                              hipStream_t stream) {
  const float* q_in = (const float*)d_in[0];
  const float* k_in = (const float*)d_in[1];
  const float* v_in = (const float*)d_in[2];
  const float* Wq = (const float*)d_in[3];
  const float* Wk = (const float*)d_in[4];
  const float* Wv = (const float*)d_in[5];
  const float* Wo = (const float*)d_in[6];

  unsigned short* qb = (unsigned short*)d_ws;   // [M,D] bf16
  unsigned short* kb = qb + (size_t)Mc * Dc;
  unsigned short* vb = kb + (size_t)Mc * Dc;
  unsigned short* ab = vb + (size_t)Mc * Dc;
  unsigned short* vt = ab + (size_t)Mc * Dc;    // V^T (key-permuted) per b

  // batched Q/K/V projections (weight cast fused into staging)
  dim3 gq(Dc / 64, Mc / 128, 3);  // (8, 64, 3) = 1536 blocks
  gemm_qkv<<<gq, 256, 0, stream>>>(q_in, k_in, v_in, Wq, Wk, Wv, qb, kb, vb);

  dim3 tg(Sc / 64, Dc / 64, Bc);
  transpose_v<<<tg, 256, 0, stream>>>(vb, vt);

  dim3 ga(Sc / 128, Bc * Hc);  // (32, 16) = 512 blocks, 512 thr
  attn_fwd<<<ga, 512, 0, stream>>>(qb, kb, vt, ab);

  dim3 gg(Dc / 64, Mc / 128);  // (8, 64)
  gemm_out<<<gg, 256, 0, stream>>>(ab, Wo, (float*)d_out);
}